// Round 10
// baseline (261.099 us; speedup 1.0000x reference)
//
#include <hip/hip_runtime.h>
#include <hip/hip_bf16.h>

#define BB_ 8
#define NN_ 8192
#define SS_ 2048
#define NS 32
#define C1 64
#define C2 64
#define C3 128
#define RAD2 0.04f
#define BN_EPS 1e-5f
#define M_TOT (BB_*SS_*NS)   // 524288
#define INV_M (1.0f/524288.0f)
#define YSTR 34              // LDS row stride (dwords): conflict-free frag reads

typedef __attribute__((ext_vector_type(8))) short bf16x8;
typedef __attribute__((ext_vector_type(4))) float f32x4;

// ws float offsets
#define FBF_OFF 0          // feat bf16 [M_TOT][8] = 2,097,152 floats (8 MB)
#define WPK_OFF 2097152    // packed weight frags: 1792 uint4
#define ST_OFF  2104320    // 512: gram[27] | sum2@64 sq2@128 | sum3@192 sq3@320
#define GMM_OFF 2104832    // float per (group, o3): 16384*128 = 2,097,152 floats (8 MB)
#define X2_OFF  4201984    // bf16 [M_TOT][64] = 64 MB (split mode only)
#define WS_NEED ((size_t)(4201984 + 16777216) * 4)

__device__ inline unsigned pkbf(float a, float b) {
    __hip_bfloat162 h = __float22bfloat162_rn(make_float2(a, b));
    unsigned r; __builtin_memcpy(&r, &h, 4); return r;
}
__device__ inline bf16x8 asfrag(uint4 v) { bf16x8 r; __builtin_memcpy(&r, &v, 16); return r; }
__device__ inline float bflo(unsigned u) { unsigned x = u << 16; float f; __builtin_memcpy(&f, &x, 4); return f; }
__device__ inline float bfhi(unsigned u) { unsigned x = u & 0xffff0000u; float f; __builtin_memcpy(&f, &x, 4); return f; }

__device__ inline void fin1_ch(const float* __restrict__ st, const float* __restrict__ W1,
                               const float* __restrict__ g, const float* __restrict__ bb,
                               int o, float* __restrict__ al, float* __restrict__ cl) {
    float w[6];
    #pragma unroll
    for (int i = 0; i < 6; ++i) w[i] = W1[o * 6 + i];
    float ms = 0.f;
    #pragma unroll
    for (int i = 0; i < 6; ++i) ms = fmaf(w[i], st[i], ms);
    float m = ms * INV_M;
    float e2 = 0.f;
    #pragma unroll
    for (int ci = 0; ci < 6; ++ci)
        #pragma unroll
        for (int d = 0; d < 6; ++d) {
            int lo = ci < d ? ci : d, hi = ci < d ? d : ci;
            int idx = 6 + lo * 6 - lo * (lo + 1) / 2 + hi;
            e2 = fmaf(w[ci] * w[d], st[idx], e2);
        }
    float var = e2 * INV_M - m * m;
    float ai = g[o] * (1.0f / sqrtf(var + BN_EPS));
    al[o] = ai;
    cl[o] = bb[o] - m * ai;
}

__device__ inline void fin_ch(const float* __restrict__ sum, const float* __restrict__ sq,
                              const float* __restrict__ g, const float* __restrict__ bb,
                              int o, float* __restrict__ al, float* __restrict__ cl) {
    float m = sum[o] * INV_M;
    float var = sq[o] * INV_M - m * m;
    float ai = g[o] * (1.0f / sqrtf(var + BN_EPS));
    al[o] = ai;
    cl[o] = bb[o] - m * ai;
}

// ---------------- front: blocks [0,4096) ball query; [4096,4104) weight pack + stat zero ----------------
__global__ void k_front(const float* __restrict__ xyz, const float* __restrict__ pts,
                        const int* __restrict__ fps, uint4* __restrict__ fbf,
                        const float* __restrict__ W1, const float* __restrict__ W2,
                        const float* __restrict__ W3, uint4* __restrict__ wf,
                        float* __restrict__ st) {
    __shared__ int lidx[4][NS];
    int tid = threadIdx.x;
    if (blockIdx.x >= 4096) {                      // ---- pack path ----
        int bb = blockIdx.x - 4096;
        if (bb == 7) { st[tid] = 0.f; st[tid + 256] = 0.f; return; }
        int t = bb * 256 + tid;   // < 1792
        int l = t & 63, p = l & 15, qd = l >> 4;
        float v[8];
        if (t < 256) {
            int mt = t >> 6;
            #pragma unroll
            for (int j = 0; j < 8; ++j)
                v[j] = (qd == 0 && j < 6) ? W1[(mt * 16 + p) * 6 + j] : 0.f;   // A[m=o1][k=c]
        } else if (t < 768) {
            int fr = (t - 256) >> 6;
            int mt = fr >> 1, kf = fr & 1;
            #pragma unroll
            for (int j = 0; j < 8; ++j)
                v[j] = W2[(16 * mt + p) * 64 + kf * 32 + qd * 8 + j];          // A[m=o2][k=c]
        } else {
            int fr = (t - 768) >> 6;
            int nt = fr >> 1, kf = fr & 1;
            #pragma unroll
            for (int j = 0; j < 8; ++j)
                v[j] = W3[(nt * 16 + p) * 64 + kf * 32 + qd * 8 + j];          // B[k=c][n=o3]
        }
        uint4 o;
        o.x = pkbf(v[0], v[1]); o.y = pkbf(v[2], v[3]);
        o.z = pkbf(v[4], v[5]); o.w = pkbf(v[6], v[7]);
        wf[t] = o;
        return;
    }
    // ---- ball query path: prefetched scan, independent waves, no barrier ----
    int wave = (blockIdx.x * blockDim.x + tid) >> 6;
    int lane = tid & 63;
    int wslot = tid >> 6;
    int b = wave / SS_;
    const float* xb = xyz + (size_t)b * 3 * NN_;
    const float* pb = pts + (size_t)b * 3 * NN_;
    int ci = fps[wave];
    float cx = xb[ci], cy = xb[NN_ + ci], cz = xb[2 * NN_ + ci];

    float px = xb[lane], py = xb[NN_ + lane], pz = xb[2 * NN_ + lane];
    int found = 0;
    int first_i = -1;
    for (int base = 0; base < NN_; base += 64) {
        float xv = px, yv = py, zv = pz;
        int nb = (base + 64 < NN_) ? base + 64 : 0;
        px = xb[nb + lane]; py = xb[NN_ + nb + lane]; pz = xb[2 * NN_ + nb + lane];
        float dx = xv - cx, dy = yv - cy, dz = zv - cz;
        float d2 = __fadd_rn(__fadd_rn(__fmul_rn(dx, dx), __fmul_rn(dy, dy)), __fmul_rn(dz, dz));
        bool inr = d2 <= RAD2;
        unsigned long long mask = __ballot(inr);
        if (first_i < 0 && mask) first_i = base + __builtin_ctzll(mask);
        if (inr) {
            int pos = found + __popcll(mask & ((1ull << lane) - 1ull));
            if (pos < NS) lidx[wslot][pos] = base + lane;
        }
        found += __popcll(mask);
        if (found >= NS) break;
    }
    if (found > NS) found = NS;
    if (lane < NS) {
        int j = (lane < found) ? lidx[wslot][lane] : first_i;
        uint4 o;
        o.x = pkbf(xb[j] - cx,           xb[NN_ + j] - cy);
        o.y = pkbf(xb[2 * NN_ + j] - cz, pb[j]);
        o.z = pkbf(pb[NN_ + j],          pb[2 * NN_ + j]);
        o.w = 0u;
        fbf[(size_t)wave * NS + lane] = o;
    }
}

// ---------------- P1: f-sums + 6x6 Gram over bf16 feat ----------------
__global__ void k_p1(const uint4* __restrict__ fbf, float* __restrict__ st) {
    __shared__ float sacc[27];
    int tid = threadIdx.x;
    if (tid < 27) sacc[tid] = 0.f;
    __syncthreads();
    int gt = blockIdx.x * 256 + tid;   // 65536 threads
    float vals[27];
    #pragma unroll
    for (int i = 0; i < 27; ++i) vals[i] = 0.f;
    #pragma unroll 1
    for (int it = 0; it < M_TOT / 65536; ++it) {
        uint4 w = fbf[it * 65536 + gt];
        float f[6] = { bflo(w.x), bfhi(w.x), bflo(w.y), bfhi(w.y), bflo(w.z), bfhi(w.z) };
        #pragma unroll
        for (int c = 0; c < 6; ++c) vals[c] += f[c];
        int q = 6;
        #pragma unroll
        for (int c = 0; c < 6; ++c)
            #pragma unroll
            for (int d = c; d < 6; ++d) { vals[q] = fmaf(f[c], f[d], vals[q]); ++q; }
    }
    int lane = tid & 63;
    #pragma unroll
    for (int i = 0; i < 27; ++i) {
        float v = vals[i];
        #pragma unroll
        for (int d = 32; d; d >>= 1) v += __shfl_xor(v, d);
        if (lane == 0) atomicAdd(&sacc[i], v);
    }
    __syncthreads();
    if (tid < 27) atomicAdd(&st[tid], sacc[tid]);
}

// ---------------- P2: layers 1-2 (transposed), x2 stats, optional x2 store ----------------
__global__ __launch_bounds__(128) void k_p2(
        const uint4* __restrict__ fbf, const uint4* __restrict__ wpk,
        float* __restrict__ st,
        const float* __restrict__ W1, const float* __restrict__ g1, const float* __restrict__ b1,
        uint2* __restrict__ x2, int store_x2) {
    __shared__ unsigned yls[2][64 * YSTR];
    __shared__ float bs[C2], bq[C2];
    __shared__ float a1ls[C1], c1ls[C1];
    int tid = threadIdx.x, wslot = tid >> 6, lane = tid & 63;
    int p = lane & 15, qd = lane >> 4;
    if (tid < C2) { bs[tid] = 0.f; bq[tid] = 0.f; fin1_ch(st, W1, g1, b1, tid, a1ls, c1ls); }
    __syncthreads();
    const uint4* w1f = wpk;
    const uint4* w2f = wpk + 256;
    unsigned* my = yls[wslot];
    float s2[4][4], q2[4][4];
    #pragma unroll
    for (int i = 0; i < 4; ++i)
        #pragma unroll
        for (int r = 0; r < 4; ++r) { s2[i][r] = 0.f; q2[i][r] = 0.f; }

    #pragma unroll 1
    for (int it = 0; it < 2; ++it) {
        int tile = it * 4096 + blockIdx.x * 2 + wslot;
        int base = tile * 64;
        bf16x8 B1[4];
        #pragma unroll
        for (int nt = 0; nt < 4; ++nt) {
            uint4 v = make_uint4(0u, 0u, 0u, 0u);
            if (qd == 0) v = fbf[base + nt * 16 + p];
            B1[nt] = asfrag(v);
        }
        #pragma unroll
        for (int mt = 0; mt < 4; ++mt) {
            bf16x8 A = asfrag(w1f[mt * 64 + lane]);
            float4 av = *(const float4*)(a1ls + mt * 16 + qd * 4);
            float4 cv = *(const float4*)(c1ls + mt * 16 + qd * 4);
            #pragma unroll
            for (int nt = 0; nt < 4; ++nt) {
                f32x4 acc = {0.f, 0.f, 0.f, 0.f};
                acc = __builtin_amdgcn_mfma_f32_16x16x32_bf16(A, B1[nt], acc, 0, 0, 0);
                float y0 = fmaxf(fmaf(av.x, acc[0], cv.x), 0.f);
                float y1 = fmaxf(fmaf(av.y, acc[1], cv.y), 0.f);
                float y2 = fmaxf(fmaf(av.z, acc[2], cv.z), 0.f);
                float y3 = fmaxf(fmaf(av.w, acc[3], cv.w), 0.f);
                int a = (nt * 16 + p) * YSTR + mt * 8 + qd * 2;
                *(uint2*)&my[a] = make_uint2(pkbf(y0, y1), pkbf(y2, y3));
            }
        }
        __syncthreads();   // phase boundary (empirically fastest: R4 vs R6/R7)
        bf16x8 B2[4][2];
        #pragma unroll
        for (int nt = 0; nt < 4; ++nt)
            #pragma unroll
            for (int kf = 0; kf < 2; ++kf)
                B2[nt][kf] = asfrag(*(const uint4*)&my[(nt * 16 + p) * YSTR + kf * 16 + qd * 4]);
        #pragma unroll
        for (int mt = 0; mt < 4; ++mt) {
            f32x4 acc[4];
            #pragma unroll
            for (int nt = 0; nt < 4; ++nt) acc[nt] = (f32x4){0.f, 0.f, 0.f, 0.f};
            #pragma unroll
            for (int kf = 0; kf < 2; ++kf) {
                bf16x8 W = asfrag(w2f[(mt * 2 + kf) * 64 + lane]);
                #pragma unroll
                for (int nt = 0; nt < 4; ++nt)
                    acc[nt] = __builtin_amdgcn_mfma_f32_16x16x32_bf16(W, B2[nt][kf], acc[nt], 0, 0, 0);
            }
            if (store_x2) {
                #pragma unroll
                for (int nt = 0; nt < 4; ++nt)
                    x2[(size_t)(tile * 64 + nt * 16 + p) * 16 + mt * 4 + qd] =
                        make_uint2(pkbf(acc[nt][0], acc[nt][1]), pkbf(acc[nt][2], acc[nt][3]));
            }
            #pragma unroll
            for (int r = 0; r < 4; ++r) {
                float u0 = acc[0][r], u1 = acc[1][r], u2 = acc[2][r], u3 = acc[3][r];
                s2[mt][r] += (u0 + u1) + (u2 + u3);
                q2[mt][r] = fmaf(u0, u0, fmaf(u1, u1, fmaf(u2, u2, fmaf(u3, u3, q2[mt][r]))));
            }
        }
        __syncthreads();
    }
    #pragma unroll
    for (int mt = 0; mt < 4; ++mt)
        #pragma unroll
        for (int r = 0; r < 4; ++r) {
            float s = s2[mt][r], q = q2[mt][r];
            #pragma unroll
            for (int off = 1; off <= 8; off <<= 1) { s += __shfl_xor(s, off); q += __shfl_xor(q, off); }
            if (p == 0) {
                atomicAdd(&bs[mt * 16 + qd * 4 + r], s);
                atomicAdd(&bq[mt * 16 + qd * 4 + r], q);
            }
        }
    __syncthreads();
    if (tid < C2) { atomicAdd(&st[64 + tid], bs[tid]); atomicAdd(&st[128 + tid], bq[tid]); }
}

// ---------------- P3 (split): layer-3 only; 1 tile/wave, mt-outer, prefetched ----------------
__global__ __launch_bounds__(256) void k_p3_l3(
        const uint2* __restrict__ x2, const uint4* __restrict__ wpk,
        float* __restrict__ st,
        const float* __restrict__ g2, const float* __restrict__ b2,
        const float* __restrict__ g3, float* __restrict__ gmm) {
    __shared__ uint4 w3ls[1024];
    __shared__ float bs[C3], bq[C3];
    __shared__ float a2ls[C2], c2ls[C2];
    int tid = threadIdx.x, wslot = tid >> 6, lane = tid & 63;
    int p = lane & 15, qd = lane >> 4;
    if (tid < 128) bs[tid] = 0.f; else bq[tid - 128] = 0.f;
    #pragma unroll
    for (int i = 0; i < 4; ++i) w3ls[i * 256 + tid] = wpk[768 + i * 256 + tid];
    if (tid < C2) fin_ch(st + 64, st + 128, g2, b2, tid, a2ls, c2ls);
    __syncthreads();
    const uint4* x2u4 = (const uint4*)x2;
    float a2r[2][8], c2r[2][8];
    #pragma unroll
    for (int kf = 0; kf < 2; ++kf)
        #pragma unroll
        for (int j = 0; j < 8; ++j) {
            a2r[kf][j] = a2ls[kf * 32 + qd * 8 + j];
            c2r[kf][j] = c2ls[kf * 32 + qd * 8 + j];
        }
    float gs3[8], gq3[8], va[8], vb[8];
    bool pos[8];
    #pragma unroll
    for (int i = 0; i < 8; ++i) {
        gs3[i] = 0.f; gq3[i] = 0.f; va[i] = -3.4e38f; vb[i] = -3.4e38f;
        pos[i] = g3[i * 16 + p] >= 0.f;
    }
    int tile = blockIdx.x * 4 + wslot;      // grid 2048 -> tiles 0..8191, ONE tile per wave
    size_t pb = (size_t)tile * 64;

    uint4 c0 = x2u4[(pb + p) * 8 + qd];
    uint4 c1 = x2u4[(pb + p) * 8 + 4 + qd];
    #pragma unroll 1
    for (int mt = 0; mt < 4; ++mt) {
        uint4 n0 = c0, n1 = c1;
        if (mt < 3) {                        // prefetch next mt while this one computes
            n0 = x2u4[(pb + (mt + 1) * 16 + p) * 8 + qd];
            n1 = x2u4[(pb + (mt + 1) * 16 + p) * 8 + 4 + qd];
        }
        // repack: affine+relu on bf16 pairs -> A-frags A[m=mt*16+p][k=kf*32+qd*8+j]
        bf16x8 A0, A1;
        {
            unsigned w0[4] = { c0.x, c0.y, c0.z, c0.w };
            unsigned w1[4] = { c1.x, c1.y, c1.z, c1.w };
            unsigned r0[4], r1[4];
            #pragma unroll
            for (int wi = 0; wi < 4; ++wi) {
                float lo0 = bflo(w0[wi]), hi0 = bfhi(w0[wi]);
                r0[wi] = pkbf(fmaxf(fmaf(a2r[0][2 * wi], lo0, c2r[0][2 * wi]), 0.f),
                              fmaxf(fmaf(a2r[0][2 * wi + 1], hi0, c2r[0][2 * wi + 1]), 0.f));
                float lo1 = bflo(w1[wi]), hi1 = bfhi(w1[wi]);
                r1[wi] = pkbf(fmaxf(fmaf(a2r[1][2 * wi], lo1, c2r[1][2 * wi]), 0.f),
                              fmaxf(fmaf(a2r[1][2 * wi + 1], hi1, c2r[1][2 * wi + 1]), 0.f));
            }
            uint4 t0 = make_uint4(r0[0], r0[1], r0[2], r0[3]);
            uint4 t1 = make_uint4(r1[0], r1[1], r1[2], r1[3]);
            A0 = asfrag(t0); A1 = asfrag(t1);
        }
        int g = mt >> 1;                     // wave-uniform group select
        #pragma unroll
        for (int nt = 0; nt < 8; ++nt) {
            bf16x8 Wa = asfrag(w3ls[(nt * 2 + 0) * 64 + lane]);
            bf16x8 Wb = asfrag(w3ls[(nt * 2 + 1) * 64 + lane]);
            f32x4 acc = __builtin_amdgcn_mfma_f32_16x16x32_bf16(A0, Wa,
                            (f32x4){0.f, 0.f, 0.f, 0.f}, 0, 0, 0);
            acc = __builtin_amdgcn_mfma_f32_16x16x32_bf16(A1, Wb, acc, 0, 0, 0);
            float v0 = acc[0], v1 = acc[1], v2 = acc[2], v3 = acc[3];
            gs3[nt] += (v0 + v1) + (v2 + v3);
            gq3[nt] = fmaf(v0, v0, fmaf(v1, v1, fmaf(v2, v2, fmaf(v3, v3, gq3[nt]))));
            float mx = fmaxf(fmaxf(v0, v1), fmaxf(v2, v3));
            float mn = fminf(fminf(v0, v1), fminf(v2, v3));
            float vv = pos[nt] ? mx : -mn;   // negate-min: always fmax-reduce
            if (g == 0) va[nt] = fmaxf(va[nt], vv);
            else        vb[nt] = fmaxf(vb[nt], vv);
        }
        c0 = n0; c1 = n1;
    }
    // extremum reduce over qd + store
    #pragma unroll
    for (int nt = 0; nt < 8; ++nt) {
        float x = va[nt], y = vb[nt];
        x = fmaxf(x, __shfl_xor(x, 16)); x = fmaxf(x, __shfl_xor(x, 32));
        y = fmaxf(y, __shfl_xor(y, 16)); y = fmaxf(y, __shfl_xor(y, 32));
        if (lane < 16) {
            gmm[(size_t)(tile * 2 + 0) * C3 + nt * 16 + lane] = x;
            gmm[(size_t)(tile * 2 + 1) * C3 + nt * 16 + lane] = y;
        }
    }
    // stats reduce over qd + block + global
    #pragma unroll
    for (int nt = 0; nt < 8; ++nt) {
        float s = gs3[nt], q = gq3[nt];
        s += __shfl_xor(s, 16); s += __shfl_xor(s, 32);
        q += __shfl_xor(q, 16); q += __shfl_xor(q, 32);
        if (lane < 16) {
            atomicAdd(&bs[nt * 16 + lane], s);
            atomicAdd(&bq[nt * 16 + lane], q);
        }
    }
    __syncthreads();
    if (tid < C3) { atomicAdd(&st[192 + tid], bs[tid]); atomicAdd(&st[320 + tid], bq[tid]); }
}

// ---------------- P3 (fallback, ws too small): fused 3 layers, R4-style barriers ----------------
__global__ __launch_bounds__(256) void k_p3_fused(
        const uint4* __restrict__ fbf, const uint4* __restrict__ wpk,
        float* __restrict__ st,
        const float* __restrict__ W1, const float* __restrict__ g1, const float* __restrict__ b1,
        const float* __restrict__ g2, const float* __restrict__ b2,
        const float* __restrict__ g3, float* __restrict__ gmm) {
    __shared__ unsigned yls[4][64 * YSTR];
    __shared__ uint4 w3ls[1024];
    __shared__ float bs[C3], bq[C3];
    __shared__ float a1ls[C1], c1ls[C1], a2ls[C2], c2ls[C2];
    int tid = threadIdx.x, wslot = tid >> 6, lane = tid & 63;
    int p = lane & 15, qd = lane >> 4;
    if (tid < 128) bs[tid] = 0.f; else bq[tid - 128] = 0.f;
    #pragma unroll
    for (int i = 0; i < 4; ++i) w3ls[i * 256 + tid] = wpk[768 + i * 256 + tid];
    if (tid < 64) fin1_ch(st, W1, g1, b1, tid, a1ls, c1ls);
    else if (tid < 128) fin_ch(st + 64, st + 128, g2, b2, tid - 64, a2ls, c2ls);
    __syncthreads();
    const uint4* w1f = wpk;
    const uint4* w2f = wpk + 256;
    unsigned* my = yls[wslot];
    float gs3[8], gq3[8];
    bool pos[8];
    #pragma unroll
    for (int i = 0; i < 8; ++i) { gs3[i] = 0.f; gq3[i] = 0.f; pos[i] = g3[i * 16 + p] >= 0.f; }

    #pragma unroll 1
    for (int it = 0; it < 2; ++it) {
        int tile = it * 4096 + blockIdx.x * 4 + wslot;
        int base = tile * 64;
        bf16x8 B1[4];
        #pragma unroll
        for (int nt = 0; nt < 4; ++nt) {
            uint4 v = make_uint4(0u, 0u, 0u, 0u);
            if (qd == 0) v = fbf[base + nt * 16 + p];
            B1[nt] = asfrag(v);
        }
        #pragma unroll
        for (int mt = 0; mt < 4; ++mt) {
            bf16x8 A = asfrag(w1f[mt * 64 + lane]);
            float4 av = *(const float4*)(a1ls + mt * 16 + qd * 4);
            float4 cv = *(const float4*)(c1ls + mt * 16 + qd * 4);
            #pragma unroll
            for (int nt = 0; nt < 4; ++nt) {
                f32x4 acc = {0.f, 0.f, 0.f, 0.f};
                acc = __builtin_amdgcn_mfma_f32_16x16x32_bf16(A, B1[nt], acc, 0, 0, 0);
                float y0 = fmaxf(fmaf(av.x, acc[0], cv.x), 0.f);
                float y1 = fmaxf(fmaf(av.y, acc[1], cv.y), 0.f);
                float y2 = fmaxf(fmaf(av.z, acc[2], cv.z), 0.f);
                float y3 = fmaxf(fmaf(av.w, acc[3], cv.w), 0.f);
                int a = (nt * 16 + p) * YSTR + mt * 8 + qd * 2;
                *(uint2*)&my[a] = make_uint2(pkbf(y0, y1), pkbf(y2, y3));
            }
        }
        __syncthreads();
        bf16x8 B2[4][2];
        #pragma unroll
        for (int nt = 0; nt < 4; ++nt)
            #pragma unroll
            for (int kf = 0; kf < 2; ++kf)
                B2[nt][kf] = asfrag(*(const uint4*)&my[(nt * 16 + p) * YSTR + kf * 16 + qd * 4]);
        __syncthreads();
        #pragma unroll
        for (int mt = 0; mt < 4; ++mt) {
            f32x4 acc[4];
            #pragma unroll
            for (int nt = 0; nt < 4; ++nt) acc[nt] = (f32x4){0.f, 0.f, 0.f, 0.f};
            #pragma unroll
            for (int kf = 0; kf < 2; ++kf) {
                bf16x8 W = asfrag(w2f[(mt * 2 + kf) * 64 + lane]);
                #pragma unroll
                for (int nt = 0; nt < 4; ++nt)
                    acc[nt] = __builtin_amdgcn_mfma_f32_16x16x32_bf16(W, B2[nt][kf], acc[nt], 0, 0, 0);
            }
            float4 av = *(const float4*)(a2ls + mt * 16 + qd * 4);
            float4 cv = *(const float4*)(c2ls + mt * 16 + qd * 4);
            #pragma unroll
            for (int nt = 0; nt < 4; ++nt) {
                float y0 = fmaxf(fmaf(av.x, acc[nt][0], cv.x), 0.f);
                float y1 = fmaxf(fmaf(av.y, acc[nt][1], cv.y), 0.f);
                float y2 = fmaxf(fmaf(av.z, acc[nt][2], cv.z), 0.f);
                float y3 = fmaxf(fmaf(av.w, acc[nt][3], cv.w), 0.f);
                int a = (nt * 16 + p) * YSTR + mt * 8 + qd * 2;
                *(uint2*)&my[a] = make_uint2(pkbf(y0, y1), pkbf(y2, y3));
            }
        }
        __syncthreads();
        bf16x8 A3[4][2];
        #pragma unroll
        for (int mt = 0; mt < 4; ++mt) {
            A3[mt][0] = asfrag(*(const uint4*)&my[(mt * 16 + p) * YSTR + qd * 4]);
            A3[mt][1] = asfrag(*(const uint4*)&my[(mt * 16 + p) * YSTR + 16 + qd * 4]);
        }
        __syncthreads();
        #pragma unroll
        for (int nt = 0; nt < 8; ++nt) {
            bf16x8 Wa = asfrag(w3ls[(nt * 2 + 0) * 64 + lane]);
            bf16x8 Wb = asfrag(w3ls[(nt * 2 + 1) * 64 + lane]);
            f32x4 acc[4];
            #pragma unroll
            for (int mt = 0; mt < 4; ++mt) {
                acc[mt] = __builtin_amdgcn_mfma_f32_16x16x32_bf16(A3[mt][0], Wa,
                            (f32x4){0.f, 0.f, 0.f, 0.f}, 0, 0, 0);
                acc[mt] = __builtin_amdgcn_mfma_f32_16x16x32_bf16(A3[mt][1], Wb, acc[mt], 0, 0, 0);
            }
            float s = 0.f, q = 0.f, va = 0.f, vb = 0.f;
            #pragma unroll
            for (int mt = 0; mt < 4; ++mt) {
                float v0 = acc[mt][0], v1 = acc[mt][1], v2 = acc[mt][2], v3 = acc[mt][3];
                s += (v0 + v1) + (v2 + v3);
                q = fmaf(v0, v0, fmaf(v1, v1, fmaf(v2, v2, fmaf(v3, v3, q))));
                float mx = fmaxf(fmaxf(v0, v1), fmaxf(v2, v3));
                float mn = fminf(fminf(v0, v1), fminf(v2, v3));
                float vv = pos[nt] ? mx : -mn;
                if (mt == 0) va = vv;
                else if (mt == 1) va = fmaxf(va, vv);
                else if (mt == 2) vb = vv;
                else vb = fmaxf(vb, vv);
            }
            gs3[nt] += s; gq3[nt] += q;
            va = fmaxf(va, __shfl_xor(va, 16)); va = fmaxf(va, __shfl_xor(va, 32));
            vb = fmaxf(vb, __shfl_xor(vb, 16)); vb = fmaxf(vb, __shfl_xor(vb, 32));
            if (lane < 16) {
                gmm[(size_t)(tile * 2 + 0) * C3 + nt * 16 + lane] = va;
                gmm[(size_t)(tile * 2 + 1) * C3 + nt * 16 + lane] = vb;
            }
        }
    }
    #pragma unroll
    for (int nt = 0; nt < 8; ++nt) {
        float s = gs3[nt], q = gq3[nt];
        s += __shfl_xor(s, 16); s += __shfl_xor(s, 32);
        q += __shfl_xor(q, 16); q += __shfl_xor(q, 32);
        if (lane < 16) {
            atomicAdd(&bs[nt * 16 + lane], s);
            atomicAdd(&bq[nt * 16 + lane], q);
        }
    }
    __syncthreads();
    if (tid < C3) { atomicAdd(&st[192 + tid], bs[tid]); atomicAdd(&st[320 + tid], bq[tid]); }
}

// ---------------- epilogue: fin3 inlined; coalesced gmm read; out + xyz ----------------
__global__ void k_outx(const float* __restrict__ gmm, const float* __restrict__ st,
                       const float* __restrict__ g3, const float* __restrict__ b3,
                       const float* __restrict__ xyz, const int* __restrict__ fps,
                       float* __restrict__ out) {
    __shared__ float T[C3][17];
    __shared__ float a3ls[C3], c3ls[C3];
    int blk = blockIdx.x, tid = threadIdx.x;
    if (blk < 1024) {
        if (tid < C3) fin_ch(st + 192, st + 320, g3, b3, tid, a3ls, c3ls);
        __syncthreads();
        int b = blk >> 7, s0 = (blk & 127) << 4;
        #pragma unroll
        for (int i = 0; i < 8; ++i) {
            int idx = i * 256 + tid;
            int sl = idx >> 7, o = idx & 127;
            float m = gmm[((size_t)(b * SS_ + s0 + sl)) * C3 + o];
            float a = a3ls[o];
            float v = (a >= 0.f) ? m : -m;
            T[o][sl] = fmaxf(fmaf(a, v, c3ls[o]), 0.f);
        }
        __syncthreads();
        int o = tid & 127, sh = tid >> 7;
        float* dst = out + (size_t)BB_ * 3 * SS_ + ((size_t)b * C3 + o) * SS_ + s0 + sh * 8;
        float4 w0, w1;
        w0.x = T[o][sh * 8 + 0]; w0.y = T[o][sh * 8 + 1];
        w0.z = T[o][sh * 8 + 2]; w0.w = T[o][sh * 8 + 3];
        w1.x = T[o][sh * 8 + 4]; w1.y = T[o][sh * 8 + 5];
        w1.z = T[o][sh * 8 + 6]; w1.w = T[o][sh * 8 + 7];
        *(float4*)dst = w0; *(float4*)(dst + 4) = w1;
    } else {
        int t = (blk - 1024) * 256 + tid;   // < 49152
        int b = t / (3 * SS_);
        int r = (t / SS_) % 3;
        int s = t % SS_;
        int ci = fps[b * SS_ + s];
        out[t] = xyz[((size_t)b * 3 + r) * NN_ + ci];
    }
}

extern "C" void kernel_launch(void* const* d_in, const int* in_sizes, int n_in,
                              void* d_out, int out_size, void* d_ws, size_t ws_size,
                              hipStream_t stream) {
    (void)in_sizes; (void)n_in; (void)out_size;
    const float* xyz = (const float*)d_in[0];
    const float* pts = (const float*)d_in[1];
    const int*   fps = (const int*)d_in[2];
    const float* W1 = (const float*)d_in[3];
    const float* g1 = (const float*)d_in[4];
    const float* b1 = (const float*)d_in[5];
    const float* W2 = (const float*)d_in[6];
    const float* g2 = (const float*)d_in[7];
    const float* b2 = (const float*)d_in[8];
    const float* W3 = (const float*)d_in[9];
    const float* g3 = (const float*)d_in[10];
    const float* b3 = (const float*)d_in[11];
    float* out = (float*)d_out;
    float* ws = (float*)d_ws;

    uint4* fbf = (uint4*)(ws + FBF_OFF);
    uint4* wpk = (uint4*)(ws + WPK_OFF);
    float* st  = ws + ST_OFF;
    float* gmm = ws + GMM_OFF;
    uint2* x2  = (uint2*)(ws + X2_OFF);
    int split = (ws_size >= WS_NEED) ? 1 : 0;   // constant across calls -> graph-safe

    k_front<<<4096 + 8, 256, 0, stream>>>(xyz, pts, fps, fbf, W1, W2, W3, wpk, st);
    k_p1<<<256, 256, 0, stream>>>(fbf, st);
    k_p2<<<2048, 128, 0, stream>>>(fbf, wpk, st, W1, g1, b1, x2, split);
    if (split)
        k_p3_l3<<<2048, 256, 0, stream>>>(x2, wpk, st, g2, b2, g3, gmm);
    else
        k_p3_fused<<<1024, 256, 0, stream>>>(fbf, wpk, st, W1, g1, b1, g2, b2, g3, gmm);
    k_outx<<<1024 + 192, 256, 0, stream>>>(gmm, st, g3, b3, xyz, fps, out);
}

// Round 11
// 247.501 us; speedup vs baseline: 1.0549x; 1.0549x over previous
//
#include <hip/hip_runtime.h>
#include <hip/hip_bf16.h>

#define BB_ 8
#define NN_ 8192
#define SS_ 2048
#define NS 32
#define C1 64
#define C2 64
#define C3 128
#define RAD2 0.04f
#define BN_EPS 1e-5f
#define M_TOT (BB_*SS_*NS)   // 524288
#define INV_M (1.0f/524288.0f)
#define YSTR 34              // LDS row stride (dwords): conflict-free frag reads

typedef __attribute__((ext_vector_type(8))) short bf16x8;
typedef __attribute__((ext_vector_type(4))) float f32x4;

// ws float offsets
#define FBF_OFF 0          // feat bf16 [M_TOT][8] = 2,097,152 floats (8 MB)
#define WPK_OFF 2097152    // packed weight frags: 1792 uint4
#define ST_OFF  2104320    // 512: gram[27] | sum2@64 sq2@128 | sum3@192 sq3@320
#define GMM_OFF 2104832    // float per (group, o3): 16384*128 = 2,097,152 floats (8 MB)
#define X2_OFF  4201984    // bf16 x2 frag-chunks: 64 MB (split mode only)
#define WS_NEED ((size_t)(4201984 + 16777216) * 4)

__device__ inline unsigned pkbf(float a, float b) {
    __hip_bfloat162 h = __float22bfloat162_rn(make_float2(a, b));
    unsigned r; __builtin_memcpy(&r, &h, 4); return r;
}
__device__ inline bf16x8 asfrag(uint4 v) { bf16x8 r; __builtin_memcpy(&r, &v, 16); return r; }
__device__ inline float bflo(unsigned u) { unsigned x = u << 16; float f; __builtin_memcpy(&f, &x, 4); return f; }
__device__ inline float bfhi(unsigned u) { unsigned x = u & 0xffff0000u; float f; __builtin_memcpy(&f, &x, 4); return f; }

__device__ inline void fin1_ch(const float* __restrict__ st, const float* __restrict__ W1,
                               const float* __restrict__ g, const float* __restrict__ bb,
                               int o, float* __restrict__ al, float* __restrict__ cl) {
    float w[6];
    #pragma unroll
    for (int i = 0; i < 6; ++i) w[i] = W1[o * 6 + i];
    float ms = 0.f;
    #pragma unroll
    for (int i = 0; i < 6; ++i) ms = fmaf(w[i], st[i], ms);
    float m = ms * INV_M;
    float e2 = 0.f;
    #pragma unroll
    for (int ci = 0; ci < 6; ++ci)
        #pragma unroll
        for (int d = 0; d < 6; ++d) {
            int lo = ci < d ? ci : d, hi = ci < d ? d : ci;
            int idx = 6 + lo * 6 - lo * (lo + 1) / 2 + hi;
            e2 = fmaf(w[ci] * w[d], st[idx], e2);
        }
    float var = e2 * INV_M - m * m;
    float ai = g[o] * (1.0f / sqrtf(var + BN_EPS));
    al[o] = ai;
    cl[o] = bb[o] - m * ai;
}

__device__ inline void fin_ch(const float* __restrict__ sum, const float* __restrict__ sq,
                              const float* __restrict__ g, const float* __restrict__ bb,
                              int o, float* __restrict__ al, float* __restrict__ cl) {
    float m = sum[o] * INV_M;
    float var = sq[o] * INV_M - m * m;
    float ai = g[o] * (1.0f / sqrtf(var + BN_EPS));
    al[o] = ai;
    cl[o] = bb[o] - m * ai;
}

// ---------------- front: blocks [0,4096) ball query; [4096,4104) weight pack + stat zero ----------------
__global__ void k_front(const float* __restrict__ xyz, const float* __restrict__ pts,
                        const int* __restrict__ fps, uint4* __restrict__ fbf,
                        const float* __restrict__ W1, const float* __restrict__ W2,
                        const float* __restrict__ W3, uint4* __restrict__ wf,
                        float* __restrict__ st) {
    __shared__ int lidx[4][NS];
    int tid = threadIdx.x;
    if (blockIdx.x >= 4096) {                      // ---- pack path ----
        int bb = blockIdx.x - 4096;
        if (bb == 7) { st[tid] = 0.f; st[tid + 256] = 0.f; return; }
        int t = bb * 256 + tid;   // < 1792
        int l = t & 63, p = l & 15, qd = l >> 4;
        float v[8];
        if (t < 256) {
            int mt = t >> 6;
            #pragma unroll
            for (int j = 0; j < 8; ++j)
                v[j] = (qd == 0 && j < 6) ? W1[(mt * 16 + p) * 6 + j] : 0.f;   // A[m=o1][k=c]
        } else if (t < 768) {
            int fr = (t - 256) >> 6;
            int mt = fr >> 1, kf = fr & 1;
            #pragma unroll
            for (int j = 0; j < 8; ++j)
                v[j] = W2[(16 * mt + p) * 64 + kf * 32 + qd * 8 + j];          // A[m=o2][k=c]
        } else {
            int fr = (t - 768) >> 6;
            int nt = fr >> 1, kf = fr & 1;
            #pragma unroll
            for (int j = 0; j < 8; ++j)
                v[j] = W3[(nt * 16 + p) * 64 + kf * 32 + qd * 8 + j];          // B[k=c][n=o3]
        }
        uint4 o;
        o.x = pkbf(v[0], v[1]); o.y = pkbf(v[2], v[3]);
        o.z = pkbf(v[4], v[5]); o.w = pkbf(v[6], v[7]);
        wf[t] = o;
        return;
    }
    // ---- ball query path: prefetched scan, independent waves, no barrier ----
    int wave = (blockIdx.x * blockDim.x + tid) >> 6;
    int lane = tid & 63;
    int wslot = tid >> 6;
    int b = wave / SS_;
    const float* xb = xyz + (size_t)b * 3 * NN_;
    const float* pb = pts + (size_t)b * 3 * NN_;
    int ci = fps[wave];
    float cx = xb[ci], cy = xb[NN_ + ci], cz = xb[2 * NN_ + ci];

    float px = xb[lane], py = xb[NN_ + lane], pz = xb[2 * NN_ + lane];
    int found = 0;
    int first_i = -1;
    for (int base = 0; base < NN_; base += 64) {
        float xv = px, yv = py, zv = pz;
        int nb = (base + 64 < NN_) ? base + 64 : 0;
        px = xb[nb + lane]; py = xb[NN_ + nb + lane]; pz = xb[2 * NN_ + nb + lane];
        float dx = xv - cx, dy = yv - cy, dz = zv - cz;
        float d2 = __fadd_rn(__fadd_rn(__fmul_rn(dx, dx), __fmul_rn(dy, dy)), __fmul_rn(dz, dz));
        bool inr = d2 <= RAD2;
        unsigned long long mask = __ballot(inr);
        if (first_i < 0 && mask) first_i = base + __builtin_ctzll(mask);
        if (inr) {
            int pos = found + __popcll(mask & ((1ull << lane) - 1ull));
            if (pos < NS) lidx[wslot][pos] = base + lane;
        }
        found += __popcll(mask);
        if (found >= NS) break;
    }
    if (found > NS) found = NS;
    if (lane < NS) {
        int j = (lane < found) ? lidx[wslot][lane] : first_i;
        uint4 o;
        o.x = pkbf(xb[j] - cx,           xb[NN_ + j] - cy);
        o.y = pkbf(xb[2 * NN_ + j] - cz, pb[j]);
        o.z = pkbf(pb[NN_ + j],          pb[2 * NN_ + j]);
        o.w = 0u;
        fbf[(size_t)wave * NS + lane] = o;
    }
}

// ---------------- P1: f-sums + 6x6 Gram over bf16 feat ----------------
__global__ void k_p1(const uint4* __restrict__ fbf, float* __restrict__ st) {
    __shared__ float sacc[27];
    int tid = threadIdx.x;
    if (tid < 27) sacc[tid] = 0.f;
    __syncthreads();
    int gt = blockIdx.x * 256 + tid;   // 65536 threads
    float vals[27];
    #pragma unroll
    for (int i = 0; i < 27; ++i) vals[i] = 0.f;
    #pragma unroll 1
    for (int it = 0; it < M_TOT / 65536; ++it) {
        uint4 w = fbf[it * 65536 + gt];
        float f[6] = { bflo(w.x), bfhi(w.x), bflo(w.y), bfhi(w.y), bflo(w.z), bfhi(w.z) };
        #pragma unroll
        for (int c = 0; c < 6; ++c) vals[c] += f[c];
        int q = 6;
        #pragma unroll
        for (int c = 0; c < 6; ++c)
            #pragma unroll
            for (int d = c; d < 6; ++d) { vals[q] = fmaf(f[c], f[d], vals[q]); ++q; }
    }
    int lane = tid & 63;
    #pragma unroll
    for (int i = 0; i < 27; ++i) {
        float v = vals[i];
        #pragma unroll
        for (int d = 32; d; d >>= 1) v += __shfl_xor(v, d);
        if (lane == 0) atomicAdd(&sacc[i], v);
    }
    __syncthreads();
    if (tid < 27) atomicAdd(&st[tid], sacc[tid]);
}

// ---------------- P2: layers 1-2 (transposed), x2 stats, coalesced x2 frag store ----------------
// x2a chunk layout: x2a[(tile*8 + mt*2 + kf)*64 + lane] = A-frag uint4 for
// point m = mt*16+p, channels k = kf*32+qd*8..+7 (pre-affine). Fully coalesced.
__global__ __launch_bounds__(128) void k_p2(
        const uint4* __restrict__ fbf, const uint4* __restrict__ wpk,
        float* __restrict__ st,
        const float* __restrict__ W1, const float* __restrict__ g1, const float* __restrict__ b1,
        uint4* __restrict__ x2a, int store_x2) {
    __shared__ unsigned yls[2][64 * YSTR];
    __shared__ float bs[C2], bq[C2];
    __shared__ float a1ls[C1], c1ls[C1];
    int tid = threadIdx.x, wslot = tid >> 6, lane = tid & 63;
    int p = lane & 15, qd = lane >> 4;
    if (tid < C2) { bs[tid] = 0.f; bq[tid] = 0.f; fin1_ch(st, W1, g1, b1, tid, a1ls, c1ls); }
    __syncthreads();
    const uint4* w1f = wpk;
    const uint4* w2f = wpk + 256;
    unsigned* my = yls[wslot];
    float s2[4][4], q2[4][4];
    #pragma unroll
    for (int i = 0; i < 4; ++i)
        #pragma unroll
        for (int r = 0; r < 4; ++r) { s2[i][r] = 0.f; q2[i][r] = 0.f; }

    #pragma unroll 1
    for (int it = 0; it < 4; ++it) {
        int tile = it * 2048 + blockIdx.x * 2 + wslot;   // R9-proven grid/iter split
        int base = tile * 64;
        bf16x8 B1[4];
        #pragma unroll
        for (int nt = 0; nt < 4; ++nt) {
            uint4 v = make_uint4(0u, 0u, 0u, 0u);
            if (qd == 0) v = fbf[base + nt * 16 + p];
            B1[nt] = asfrag(v);
        }
        #pragma unroll
        for (int mt = 0; mt < 4; ++mt) {
            bf16x8 A = asfrag(w1f[mt * 64 + lane]);
            float4 av = *(const float4*)(a1ls + mt * 16 + qd * 4);
            float4 cv = *(const float4*)(c1ls + mt * 16 + qd * 4);
            #pragma unroll
            for (int nt = 0; nt < 4; ++nt) {
                f32x4 acc = {0.f, 0.f, 0.f, 0.f};
                acc = __builtin_amdgcn_mfma_f32_16x16x32_bf16(A, B1[nt], acc, 0, 0, 0);
                float y0 = fmaxf(fmaf(av.x, acc[0], cv.x), 0.f);
                float y1 = fmaxf(fmaf(av.y, acc[1], cv.y), 0.f);
                float y2 = fmaxf(fmaf(av.z, acc[2], cv.z), 0.f);
                float y3 = fmaxf(fmaf(av.w, acc[3], cv.w), 0.f);
                int a = (nt * 16 + p) * YSTR + mt * 8 + qd * 2;
                *(uint2*)&my[a] = make_uint2(pkbf(y0, y1), pkbf(y2, y3));
            }
        }
        __syncthreads();   // y1 writes -> B2 reads
        bf16x8 B2[4][2];
        #pragma unroll
        for (int nt = 0; nt < 4; ++nt)
            #pragma unroll
            for (int kf = 0; kf < 2; ++kf)
                B2[nt][kf] = asfrag(*(const uint4*)&my[(nt * 16 + p) * YSTR + kf * 16 + qd * 4]);
        __syncthreads();   // B2 reads -> x2 LDS overwrite
        #pragma unroll
        for (int mt = 0; mt < 4; ++mt) {
            f32x4 acc[4];
            #pragma unroll
            for (int nt = 0; nt < 4; ++nt) acc[nt] = (f32x4){0.f, 0.f, 0.f, 0.f};
            #pragma unroll
            for (int kf = 0; kf < 2; ++kf) {
                bf16x8 W = asfrag(w2f[(mt * 2 + kf) * 64 + lane]);
                #pragma unroll
                for (int nt = 0; nt < 4; ++nt)
                    acc[nt] = __builtin_amdgcn_mfma_f32_16x16x32_bf16(W, B2[nt][kf], acc[nt], 0, 0, 0);
            }
            // pre-affine x2 into LDS rows [pt][ch] (channels mt*16+qd*4..+3)
            if (store_x2) {
                #pragma unroll
                for (int nt = 0; nt < 4; ++nt) {
                    int a = (nt * 16 + p) * YSTR + mt * 8 + qd * 2;
                    *(uint2*)&my[a] = make_uint2(pkbf(acc[nt][0], acc[nt][1]),
                                                 pkbf(acc[nt][2], acc[nt][3]));
                }
            }
            #pragma unroll
            for (int r = 0; r < 4; ++r) {
                float u0 = acc[0][r], u1 = acc[1][r], u2 = acc[2][r], u3 = acc[3][r];
                s2[mt][r] += (u0 + u1) + (u2 + u3);
                q2[mt][r] = fmaf(u0, u0, fmaf(u1, u1, fmaf(u2, u2, fmaf(u3, u3, q2[mt][r]))));
            }
        }
        if (store_x2) {
            __syncthreads();   // x2 LDS writes -> frag reads
            #pragma unroll
            for (int mtc = 0; mtc < 4; ++mtc)
                #pragma unroll
                for (int kf = 0; kf < 2; ++kf) {
                    uint4 v = *(const uint4*)&my[(mtc * 16 + p) * YSTR + kf * 16 + qd * 4];
                    x2a[((size_t)tile * 8 + mtc * 2 + kf) * 64 + lane] = v;   // 1 KB coalesced
                }
        }
        __syncthreads();   // tile done -> next iter overwrites LDS
    }
    #pragma unroll
    for (int mt = 0; mt < 4; ++mt)
        #pragma unroll
        for (int r = 0; r < 4; ++r) {
            float s = s2[mt][r], q = q2[mt][r];
            #pragma unroll
            for (int off = 1; off <= 8; off <<= 1) { s += __shfl_xor(s, off); q += __shfl_xor(q, off); }
            if (p == 0) {
                atomicAdd(&bs[mt * 16 + qd * 4 + r], s);
                atomicAdd(&bq[mt * 16 + qd * 4 + r], q);
            }
        }
    __syncthreads();
    if (tid < C2) { atomicAdd(&st[64 + tid], bs[tid]); atomicAdd(&st[128 + tid], bq[tid]); }
}

// ---------------- P3 (split): layer-3 only; 1 tile/wave; coalesced frag loads ----------------
__global__ __launch_bounds__(256) void k_p3_l3(
        const uint4* __restrict__ x2a, const uint4* __restrict__ wpk,
        float* __restrict__ st,
        const float* __restrict__ g2, const float* __restrict__ b2,
        const float* __restrict__ g3, float* __restrict__ gmm) {
    __shared__ uint4 w3ls[1024];
    __shared__ float bs[C3], bq[C3];
    __shared__ float a2ls[C2], c2ls[C2];
    int tid = threadIdx.x, wslot = tid >> 6, lane = tid & 63;
    int p = lane & 15, qd = lane >> 4;
    if (tid < 128) bs[tid] = 0.f; else bq[tid - 128] = 0.f;
    #pragma unroll
    for (int i = 0; i < 4; ++i) w3ls[i * 256 + tid] = wpk[768 + i * 256 + tid];
    if (tid < C2) fin_ch(st + 64, st + 128, g2, b2, tid, a2ls, c2ls);
    __syncthreads();
    float a2r[2][8], c2r[2][8];
    #pragma unroll
    for (int kf = 0; kf < 2; ++kf)
        #pragma unroll
        for (int j = 0; j < 8; ++j) {
            a2r[kf][j] = a2ls[kf * 32 + qd * 8 + j];
            c2r[kf][j] = c2ls[kf * 32 + qd * 8 + j];
        }
    float gs3[8], gq3[8], va[8], vb[8];
    bool pos[8];
    #pragma unroll
    for (int i = 0; i < 8; ++i) {
        gs3[i] = 0.f; gq3[i] = 0.f; va[i] = -3.4e38f; vb[i] = -3.4e38f;
        pos[i] = g3[i * 16 + p] >= 0.f;
    }
    int tile = blockIdx.x * 4 + wslot;      // grid 2048 -> one tile per wave
    size_t cb = (size_t)tile * 8;

    uint4 c0 = x2a[(cb + 0) * 64 + lane];   // coalesced 1-KB chunk loads
    uint4 c1 = x2a[(cb + 1) * 64 + lane];
    #pragma unroll 1
    for (int mt = 0; mt < 4; ++mt) {
        uint4 n0 = c0, n1 = c1;
        if (mt < 3) {                        // prefetch next mt while this one computes
            n0 = x2a[(cb + (mt + 1) * 2 + 0) * 64 + lane];
            n1 = x2a[(cb + (mt + 1) * 2 + 1) * 64 + lane];
        }
        // affine+relu+repack -> A-frags A[m=mt*16+p][k=kf*32+qd*8+j]
        bf16x8 A0, A1;
        {
            unsigned w0[4] = { c0.x, c0.y, c0.z, c0.w };
            unsigned w1[4] = { c1.x, c1.y, c1.z, c1.w };
            unsigned r0[4], r1[4];
            #pragma unroll
            for (int wi = 0; wi < 4; ++wi) {
                float lo0 = bflo(w0[wi]), hi0 = bfhi(w0[wi]);
                r0[wi] = pkbf(fmaxf(fmaf(a2r[0][2 * wi], lo0, c2r[0][2 * wi]), 0.f),
                              fmaxf(fmaf(a2r[0][2 * wi + 1], hi0, c2r[0][2 * wi + 1]), 0.f));
                float lo1 = bflo(w1[wi]), hi1 = bfhi(w1[wi]);
                r1[wi] = pkbf(fmaxf(fmaf(a2r[1][2 * wi], lo1, c2r[1][2 * wi]), 0.f),
                              fmaxf(fmaf(a2r[1][2 * wi + 1], hi1, c2r[1][2 * wi + 1]), 0.f));
            }
            uint4 t0 = make_uint4(r0[0], r0[1], r0[2], r0[3]);
            uint4 t1 = make_uint4(r1[0], r1[1], r1[2], r1[3]);
            A0 = asfrag(t0); A1 = asfrag(t1);
        }
        int g = mt >> 1;                     // wave-uniform group select
        #pragma unroll
        for (int nt = 0; nt < 8; ++nt) {
            bf16x8 Wa = asfrag(w3ls[(nt * 2 + 0) * 64 + lane]);
            bf16x8 Wb = asfrag(w3ls[(nt * 2 + 1) * 64 + lane]);
            f32x4 acc = __builtin_amdgcn_mfma_f32_16x16x32_bf16(A0, Wa,
                            (f32x4){0.f, 0.f, 0.f, 0.f}, 0, 0, 0);
            acc = __builtin_amdgcn_mfma_f32_16x16x32_bf16(A1, Wb, acc, 0, 0, 0);
            float v0 = acc[0], v1 = acc[1], v2 = acc[2], v3 = acc[3];
            gs3[nt] += (v0 + v1) + (v2 + v3);
            gq3[nt] = fmaf(v0, v0, fmaf(v1, v1, fmaf(v2, v2, fmaf(v3, v3, gq3[nt]))));
            float mx = fmaxf(fmaxf(v0, v1), fmaxf(v2, v3));
            float mn = fminf(fminf(v0, v1), fminf(v2, v3));
            float vv = pos[nt] ? mx : -mn;   // negate-min: always fmax-reduce
            if (g == 0) va[nt] = fmaxf(va[nt], vv);
            else        vb[nt] = fmaxf(vb[nt], vv);
        }
        c0 = n0; c1 = n1;
    }
    #pragma unroll
    for (int nt = 0; nt < 8; ++nt) {
        float x = va[nt], y = vb[nt];
        x = fmaxf(x, __shfl_xor(x, 16)); x = fmaxf(x, __shfl_xor(x, 32));
        y = fmaxf(y, __shfl_xor(y, 16)); y = fmaxf(y, __shfl_xor(y, 32));
        if (lane < 16) {
            gmm[(size_t)(tile * 2 + 0) * C3 + nt * 16 + lane] = x;
            gmm[(size_t)(tile * 2 + 1) * C3 + nt * 16 + lane] = y;
        }
    }
    #pragma unroll
    for (int nt = 0; nt < 8; ++nt) {
        float s = gs3[nt], q = gq3[nt];
        s += __shfl_xor(s, 16); s += __shfl_xor(s, 32);
        q += __shfl_xor(q, 16); q += __shfl_xor(q, 32);
        if (lane < 16) {
            atomicAdd(&bs[nt * 16 + lane], s);
            atomicAdd(&bq[nt * 16 + lane], q);
        }
    }
    __syncthreads();
    if (tid < C3) { atomicAdd(&st[192 + tid], bs[tid]); atomicAdd(&st[320 + tid], bq[tid]); }
}

// ---------------- P3 (fallback, ws too small): fused 3 layers, R4-style barriers ----------------
__global__ __launch_bounds__(256) void k_p3_fused(
        const uint4* __restrict__ fbf, const uint4* __restrict__ wpk,
        float* __restrict__ st,
        const float* __restrict__ W1, const float* __restrict__ g1, const float* __restrict__ b1,
        const float* __restrict__ g2, const float* __restrict__ b2,
        const float* __restrict__ g3, float* __restrict__ gmm) {
    __shared__ unsigned yls[4][64 * YSTR];
    __shared__ uint4 w3ls[1024];
    __shared__ float bs[C3], bq[C3];
    __shared__ float a1ls[C1], c1ls[C1], a2ls[C2], c2ls[C2];
    int tid = threadIdx.x, wslot = tid >> 6, lane = tid & 63;
    int p = lane & 15, qd = lane >> 4;
    if (tid < 128) bs[tid] = 0.f; else bq[tid - 128] = 0.f;
    #pragma unroll
    for (int i = 0; i < 4; ++i) w3ls[i * 256 + tid] = wpk[768 + i * 256 + tid];
    if (tid < 64) fin1_ch(st, W1, g1, b1, tid, a1ls, c1ls);
    else if (tid < 128) fin_ch(st + 64, st + 128, g2, b2, tid - 64, a2ls, c2ls);
    __syncthreads();
    const uint4* w1f = wpk;
    const uint4* w2f = wpk + 256;
    unsigned* my = yls[wslot];
    float gs3[8], gq3[8];
    bool pos[8];
    #pragma unroll
    for (int i = 0; i < 8; ++i) { gs3[i] = 0.f; gq3[i] = 0.f; pos[i] = g3[i * 16 + p] >= 0.f; }

    #pragma unroll 1
    for (int it = 0; it < 2; ++it) {
        int tile = it * 4096 + blockIdx.x * 4 + wslot;
        int base = tile * 64;
        bf16x8 B1[4];
        #pragma unroll
        for (int nt = 0; nt < 4; ++nt) {
            uint4 v = make_uint4(0u, 0u, 0u, 0u);
            if (qd == 0) v = fbf[base + nt * 16 + p];
            B1[nt] = asfrag(v);
        }
        #pragma unroll
        for (int mt = 0; mt < 4; ++mt) {
            bf16x8 A = asfrag(w1f[mt * 64 + lane]);
            float4 av = *(const float4*)(a1ls + mt * 16 + qd * 4);
            float4 cv = *(const float4*)(c1ls + mt * 16 + qd * 4);
            #pragma unroll
            for (int nt = 0; nt < 4; ++nt) {
                f32x4 acc = {0.f, 0.f, 0.f, 0.f};
                acc = __builtin_amdgcn_mfma_f32_16x16x32_bf16(A, B1[nt], acc, 0, 0, 0);
                float y0 = fmaxf(fmaf(av.x, acc[0], cv.x), 0.f);
                float y1 = fmaxf(fmaf(av.y, acc[1], cv.y), 0.f);
                float y2 = fmaxf(fmaf(av.z, acc[2], cv.z), 0.f);
                float y3 = fmaxf(fmaf(av.w, acc[3], cv.w), 0.f);
                int a = (nt * 16 + p) * YSTR + mt * 8 + qd * 2;
                *(uint2*)&my[a] = make_uint2(pkbf(y0, y1), pkbf(y2, y3));
            }
        }
        __syncthreads();
        bf16x8 B2[4][2];
        #pragma unroll
        for (int nt = 0; nt < 4; ++nt)
            #pragma unroll
            for (int kf = 0; kf < 2; ++kf)
                B2[nt][kf] = asfrag(*(const uint4*)&my[(nt * 16 + p) * YSTR + kf * 16 + qd * 4]);
        __syncthreads();
        #pragma unroll
        for (int mt = 0; mt < 4; ++mt) {
            f32x4 acc[4];
            #pragma unroll
            for (int nt = 0; nt < 4; ++nt) acc[nt] = (f32x4){0.f, 0.f, 0.f, 0.f};
            #pragma unroll
            for (int kf = 0; kf < 2; ++kf) {
                bf16x8 W = asfrag(w2f[(mt * 2 + kf) * 64 + lane]);
                #pragma unroll
                for (int nt = 0; nt < 4; ++nt)
                    acc[nt] = __builtin_amdgcn_mfma_f32_16x16x32_bf16(W, B2[nt][kf], acc[nt], 0, 0, 0);
            }
            float4 av = *(const float4*)(a2ls + mt * 16 + qd * 4);
            float4 cv = *(const float4*)(c2ls + mt * 16 + qd * 4);
            #pragma unroll
            for (int nt = 0; nt < 4; ++nt) {
                float y0 = fmaxf(fmaf(av.x, acc[nt][0], cv.x), 0.f);
                float y1 = fmaxf(fmaf(av.y, acc[nt][1], cv.y), 0.f);
                float y2 = fmaxf(fmaf(av.z, acc[nt][2], cv.z), 0.f);
                float y3 = fmaxf(fmaf(av.w, acc[nt][3], cv.w), 0.f);
                int a = (nt * 16 + p) * YSTR + mt * 8 + qd * 2;
                *(uint2*)&my[a] = make_uint2(pkbf(y0, y1), pkbf(y2, y3));
            }
        }
        __syncthreads();
        bf16x8 A3[4][2];
        #pragma unroll
        for (int mt = 0; mt < 4; ++mt) {
            A3[mt][0] = asfrag(*(const uint4*)&my[(mt * 16 + p) * YSTR + qd * 4]);
            A3[mt][1] = asfrag(*(const uint4*)&my[(mt * 16 + p) * YSTR + 16 + qd * 4]);
        }
        __syncthreads();
        #pragma unroll
        for (int nt = 0; nt < 8; ++nt) {
            bf16x8 Wa = asfrag(w3ls[(nt * 2 + 0) * 64 + lane]);
            bf16x8 Wb = asfrag(w3ls[(nt * 2 + 1) * 64 + lane]);
            f32x4 acc[4];
            #pragma unroll
            for (int mt = 0; mt < 4; ++mt) {
                acc[mt] = __builtin_amdgcn_mfma_f32_16x16x32_bf16(A3[mt][0], Wa,
                            (f32x4){0.f, 0.f, 0.f, 0.f}, 0, 0, 0);
                acc[mt] = __builtin_amdgcn_mfma_f32_16x16x32_bf16(A3[mt][1], Wb, acc[mt], 0, 0, 0);
            }
            float s = 0.f, q = 0.f, va = 0.f, vb = 0.f;
            #pragma unroll
            for (int mt = 0; mt < 4; ++mt) {
                float v0 = acc[mt][0], v1 = acc[mt][1], v2 = acc[mt][2], v3 = acc[mt][3];
                s += (v0 + v1) + (v2 + v3);
                q = fmaf(v0, v0, fmaf(v1, v1, fmaf(v2, v2, fmaf(v3, v3, q))));
                float mx = fmaxf(fmaxf(v0, v1), fmaxf(v2, v3));
                float mn = fminf(fminf(v0, v1), fminf(v2, v3));
                float vv = pos[nt] ? mx : -mn;
                if (mt == 0) va = vv;
                else if (mt == 1) va = fmaxf(va, vv);
                else if (mt == 2) vb = vv;
                else vb = fmaxf(vb, vv);
            }
            gs3[nt] += s; gq3[nt] += q;
            va = fmaxf(va, __shfl_xor(va, 16)); va = fmaxf(va, __shfl_xor(va, 32));
            vb = fmaxf(vb, __shfl_xor(vb, 16)); vb = fmaxf(vb, __shfl_xor(vb, 32));
            if (lane < 16) {
                gmm[(size_t)(tile * 2 + 0) * C3 + nt * 16 + lane] = va;
                gmm[(size_t)(tile * 2 + 1) * C3 + nt * 16 + lane] = vb;
            }
        }
    }
    #pragma unroll
    for (int nt = 0; nt < 8; ++nt) {
        float s = gs3[nt], q = gq3[nt];
        s += __shfl_xor(s, 16); s += __shfl_xor(s, 32);
        q += __shfl_xor(q, 16); q += __shfl_xor(q, 32);
        if (lane < 16) {
            atomicAdd(&bs[nt * 16 + lane], s);
            atomicAdd(&bq[nt * 16 + lane], q);
        }
    }
    __syncthreads();
    if (tid < C3) { atomicAdd(&st[192 + tid], bs[tid]); atomicAdd(&st[320 + tid], bq[tid]); }
}

// ---------------- epilogue: fin3 inlined; coalesced gmm read; out + xyz ----------------
__global__ void k_outx(const float* __restrict__ gmm, const float* __restrict__ st,
                       const float* __restrict__ g3, const float* __restrict__ b3,
                       const float* __restrict__ xyz, const int* __restrict__ fps,
                       float* __restrict__ out) {
    __shared__ float T[C3][17];
    __shared__ float a3ls[C3], c3ls[C3];
    int blk = blockIdx.x, tid = threadIdx.x;
    if (blk < 1024) {
        if (tid < C3) fin_ch(st + 192, st + 320, g3, b3, tid, a3ls, c3ls);
        __syncthreads();
        int b = blk >> 7, s0 = (blk & 127) << 4;
        #pragma unroll
        for (int i = 0; i < 8; ++i) {
            int idx = i * 256 + tid;
            int sl = idx >> 7, o = idx & 127;
            float m = gmm[((size_t)(b * SS_ + s0 + sl)) * C3 + o];
            float a = a3ls[o];
            float v = (a >= 0.f) ? m : -m;
            T[o][sl] = fmaxf(fmaf(a, v, c3ls[o]), 0.f);
        }
        __syncthreads();
        int o = tid & 127, sh = tid >> 7;
        float* dst = out + (size_t)BB_ * 3 * SS_ + ((size_t)b * C3 + o) * SS_ + s0 + sh * 8;
        float4 w0, w1;
        w0.x = T[o][sh * 8 + 0]; w0.y = T[o][sh * 8 + 1];
        w0.z = T[o][sh * 8 + 2]; w0.w = T[o][sh * 8 + 3];
        w1.x = T[o][sh * 8 + 4]; w1.y = T[o][sh * 8 + 5];
        w1.z = T[o][sh * 8 + 6]; w1.w = T[o][sh * 8 + 7];
        *(float4*)dst = w0; *(float4*)(dst + 4) = w1;
    } else {
        int t = (blk - 1024) * 256 + tid;   // < 49152
        int b = t / (3 * SS_);
        int r = (t / SS_) % 3;
        int s = t % SS_;
        int ci = fps[b * SS_ + s];
        out[t] = xyz[((size_t)b * 3 + r) * NN_ + ci];
    }
}

extern "C" void kernel_launch(void* const* d_in, const int* in_sizes, int n_in,
                              void* d_out, int out_size, void* d_ws, size_t ws_size,
                              hipStream_t stream) {
    (void)in_sizes; (void)n_in; (void)out_size;
    const float* xyz = (const float*)d_in[0];
    const float* pts = (const float*)d_in[1];
    const int*   fps = (const int*)d_in[2];
    const float* W1 = (const float*)d_in[3];
    const float* g1 = (const float*)d_in[4];
    const float* b1 = (const float*)d_in[5];
    const float* W2 = (const float*)d_in[6];
    const float* g2 = (const float*)d_in[7];
    const float* b2 = (const float*)d_in[8];
    const float* W3 = (const float*)d_in[9];
    const float* g3 = (const float*)d_in[10];
    const float* b3 = (const float*)d_in[11];
    float* out = (float*)d_out;
    float* ws = (float*)d_ws;

    uint4* fbf = (uint4*)(ws + FBF_OFF);
    uint4* wpk = (uint4*)(ws + WPK_OFF);
    float* st  = ws + ST_OFF;
    float* gmm = ws + GMM_OFF;
    uint4* x2a = (uint4*)(ws + X2_OFF);
    int split = (ws_size >= WS_NEED) ? 1 : 0;   // constant across calls -> graph-safe

    k_front<<<4096 + 8, 256, 0, stream>>>(xyz, pts, fps, fbf, W1, W2, W3, wpk, st);
    k_p1<<<256, 256, 0, stream>>>(fbf, st);
    k_p2<<<1024, 128, 0, stream>>>(fbf, wpk, st, W1, g1, b1, x2a, split);
    if (split)
        k_p3_l3<<<2048, 256, 0, stream>>>(x2a, wpk, st, g2, b2, g3, gmm);
    else
        k_p3_fused<<<1024, 256, 0, stream>>>(fbf, wpk, st, W1, g1, b1, g2, b2, g3, gmm);
    k_outx<<<1024 + 192, 256, 0, stream>>>(gmm, st, g3, b3, xyz, fps, out);
}

// Round 12
// 225.981 us; speedup vs baseline: 1.1554x; 1.0952x over previous
//
#include <hip/hip_runtime.h>
#include <hip/hip_bf16.h>

#define BB_ 8
#define NN_ 8192
#define SS_ 2048
#define NS 32
#define C1 64
#define C2 64
#define C3 128
#define RAD2 0.04f
#define BN_EPS 1e-5f
#define M_TOT (BB_*SS_*NS)   // 524288
#define INV_M (1.0f/524288.0f)
#define YSTR 34              // LDS row stride (dwords): conflict-free frag reads

typedef __attribute__((ext_vector_type(8))) short bf16x8;
typedef __attribute__((ext_vector_type(4))) float f32x4;

// ws float offsets
#define FBF_OFF 0          // feat bf16 [M_TOT][8] = 2,097,152 floats (8 MB)
#define WPK_OFF 2097152    // packed weight frags: 1792 uint4
#define ST_OFF  2104320    // 512: gram[27] | sum2@64 sq2@128 | sum3@192 sq3@320
#define GMM_OFF 2104832    // float per (group, o3): 16384*128 = 2,097,152 floats (8 MB)
#define X2_OFF  4201984    // bf16 x2 frag-chunks: 64 MB (split mode only)
#define WS_NEED ((size_t)(4201984 + 16777216) * 4)

__device__ inline unsigned pkbf(float a, float b) {
    __hip_bfloat162 h = __float22bfloat162_rn(make_float2(a, b));
    unsigned r; __builtin_memcpy(&r, &h, 4); return r;
}
__device__ inline bf16x8 asfrag(uint4 v) { bf16x8 r; __builtin_memcpy(&r, &v, 16); return r; }
__device__ inline float bflo(unsigned u) { unsigned x = u << 16; float f; __builtin_memcpy(&f, &x, 4); return f; }
__device__ inline float bfhi(unsigned u) { unsigned x = u & 0xffff0000u; float f; __builtin_memcpy(&f, &x, 4); return f; }

__device__ inline void fin1_ch(const float* __restrict__ st, const float* __restrict__ W1,
                               const float* __restrict__ g, const float* __restrict__ bb,
                               int o, float* __restrict__ al, float* __restrict__ cl) {
    float w[6];
    #pragma unroll
    for (int i = 0; i < 6; ++i) w[i] = W1[o * 6 + i];
    float ms = 0.f;
    #pragma unroll
    for (int i = 0; i < 6; ++i) ms = fmaf(w[i], st[i], ms);
    float m = ms * INV_M;
    float e2 = 0.f;
    #pragma unroll
    for (int ci = 0; ci < 6; ++ci)
        #pragma unroll
        for (int d = 0; d < 6; ++d) {
            int lo = ci < d ? ci : d, hi = ci < d ? d : ci;
            int idx = 6 + lo * 6 - lo * (lo + 1) / 2 + hi;
            e2 = fmaf(w[ci] * w[d], st[idx], e2);
        }
    float var = e2 * INV_M - m * m;
    float ai = g[o] * (1.0f / sqrtf(var + BN_EPS));
    al[o] = ai;
    cl[o] = bb[o] - m * ai;
}

__device__ inline void fin_ch(const float* __restrict__ sum, const float* __restrict__ sq,
                              const float* __restrict__ g, const float* __restrict__ bb,
                              int o, float* __restrict__ al, float* __restrict__ cl) {
    float m = sum[o] * INV_M;
    float var = sq[o] * INV_M - m * m;
    float ai = g[o] * (1.0f / sqrtf(var + BN_EPS));
    al[o] = ai;
    cl[o] = bb[o] - m * ai;
}

// ---------------- front: blocks [0,4096) ball query; [4096,4104) weight pack + stat zero ----------------
__global__ void k_front(const float* __restrict__ xyz, const float* __restrict__ pts,
                        const int* __restrict__ fps, uint4* __restrict__ fbf,
                        const float* __restrict__ W1, const float* __restrict__ W2,
                        const float* __restrict__ W3, uint4* __restrict__ wf,
                        float* __restrict__ st) {
    __shared__ int lidx[4][NS];
    int tid = threadIdx.x;
    if (blockIdx.x >= 4096) {                      // ---- pack path ----
        int bb = blockIdx.x - 4096;
        if (bb == 7) { st[tid] = 0.f; st[tid + 256] = 0.f; return; }
        int t = bb * 256 + tid;   // < 1792
        int l = t & 63, p = l & 15, qd = l >> 4;
        float v[8];
        if (t < 256) {
            int mt = t >> 6;
            #pragma unroll
            for (int j = 0; j < 8; ++j)
                v[j] = (qd == 0 && j < 6) ? W1[(mt * 16 + p) * 6 + j] : 0.f;   // A[m=o1][k=c]
        } else if (t < 768) {
            int fr = (t - 256) >> 6;
            int mt = fr >> 1, kf = fr & 1;
            #pragma unroll
            for (int j = 0; j < 8; ++j)
                v[j] = W2[(16 * mt + p) * 64 + kf * 32 + qd * 8 + j];          // A[m=o2][k=c]
        } else {
            int fr = (t - 768) >> 6;
            int nt = fr >> 1, kf = fr & 1;
            #pragma unroll
            for (int j = 0; j < 8; ++j)
                v[j] = W3[(nt * 16 + p) * 64 + kf * 32 + qd * 8 + j];          // B[k=c][n=o3]
        }
        uint4 o;
        o.x = pkbf(v[0], v[1]); o.y = pkbf(v[2], v[3]);
        o.z = pkbf(v[4], v[5]); o.w = pkbf(v[6], v[7]);
        wf[t] = o;
        return;
    }
    // ---- ball query path: prefetched scan, independent waves, no barrier ----
    int wave = (blockIdx.x * blockDim.x + tid) >> 6;
    int lane = tid & 63;
    int wslot = tid >> 6;
    int b = wave / SS_;
    const float* xb = xyz + (size_t)b * 3 * NN_;
    const float* pb = pts + (size_t)b * 3 * NN_;
    int ci = fps[wave];
    float cx = xb[ci], cy = xb[NN_ + ci], cz = xb[2 * NN_ + ci];

    float px = xb[lane], py = xb[NN_ + lane], pz = xb[2 * NN_ + lane];
    int found = 0;
    int first_i = -1;
    for (int base = 0; base < NN_; base += 64) {
        float xv = px, yv = py, zv = pz;
        int nb = (base + 64 < NN_) ? base + 64 : 0;
        px = xb[nb + lane]; py = xb[NN_ + nb + lane]; pz = xb[2 * NN_ + nb + lane];
        float dx = xv - cx, dy = yv - cy, dz = zv - cz;
        float d2 = __fadd_rn(__fadd_rn(__fmul_rn(dx, dx), __fmul_rn(dy, dy)), __fmul_rn(dz, dz));
        bool inr = d2 <= RAD2;
        unsigned long long mask = __ballot(inr);
        if (first_i < 0 && mask) first_i = base + __builtin_ctzll(mask);
        if (inr) {
            int pos = found + __popcll(mask & ((1ull << lane) - 1ull));
            if (pos < NS) lidx[wslot][pos] = base + lane;
        }
        found += __popcll(mask);
        if (found >= NS) break;
    }
    if (found > NS) found = NS;
    if (lane < NS) {
        int j = (lane < found) ? lidx[wslot][lane] : first_i;
        uint4 o;
        o.x = pkbf(xb[j] - cx,           xb[NN_ + j] - cy);
        o.y = pkbf(xb[2 * NN_ + j] - cz, pb[j]);
        o.z = pkbf(pb[NN_ + j],          pb[2 * NN_ + j]);
        o.w = 0u;
        fbf[(size_t)wave * NS + lane] = o;
    }
}

// ---------------- P1: f-sums + 6x6 Gram over bf16 feat ----------------
__global__ void k_p1(const uint4* __restrict__ fbf, float* __restrict__ st) {
    __shared__ float sacc[27];
    int tid = threadIdx.x;
    if (tid < 27) sacc[tid] = 0.f;
    __syncthreads();
    int gt = blockIdx.x * 256 + tid;   // 65536 threads
    float vals[27];
    #pragma unroll
    for (int i = 0; i < 27; ++i) vals[i] = 0.f;
    #pragma unroll 1
    for (int it = 0; it < M_TOT / 65536; ++it) {
        uint4 w = fbf[it * 65536 + gt];
        float f[6] = { bflo(w.x), bfhi(w.x), bflo(w.y), bfhi(w.y), bflo(w.z), bfhi(w.z) };
        #pragma unroll
        for (int c = 0; c < 6; ++c) vals[c] += f[c];
        int q = 6;
        #pragma unroll
        for (int c = 0; c < 6; ++c)
            #pragma unroll
            for (int d = c; d < 6; ++d) { vals[q] = fmaf(f[c], f[d], vals[q]); ++q; }
    }
    int lane = tid & 63;
    #pragma unroll
    for (int i = 0; i < 27; ++i) {
        float v = vals[i];
        #pragma unroll
        for (int d = 32; d; d >>= 1) v += __shfl_xor(v, d);
        if (lane == 0) atomicAdd(&sacc[i], v);
    }
    __syncthreads();
    if (tid < 27) atomicAdd(&st[tid], sacc[tid]);
}

// ---------------- P2: layers 1-2 (transposed), x2 stats, coalesced x2 frag store ----------------
// x2a chunk layout: x2a[(tile*8 + mt*2 + kf)*64 + lane] = A-frag uint4 for
// point m = mt*16+p, channels k = kf*32+qd*8..+7 (pre-affine). Fully coalesced.
__global__ __launch_bounds__(128) void k_p2(
        const uint4* __restrict__ fbf, const uint4* __restrict__ wpk,
        float* __restrict__ st,
        const float* __restrict__ W1, const float* __restrict__ g1, const float* __restrict__ b1,
        uint4* __restrict__ x2a, int store_x2) {
    __shared__ unsigned yls[2][64 * YSTR];
    __shared__ float bs[C2], bq[C2];
    __shared__ float a1ls[C1], c1ls[C1];
    int tid = threadIdx.x, wslot = tid >> 6, lane = tid & 63;
    int p = lane & 15, qd = lane >> 4;
    if (tid < C2) { bs[tid] = 0.f; bq[tid] = 0.f; fin1_ch(st, W1, g1, b1, tid, a1ls, c1ls); }
    __syncthreads();
    const uint4* w1f = wpk;
    const uint4* w2f = wpk + 256;
    unsigned* my = yls[wslot];
    float s2[4][4], q2[4][4];
    #pragma unroll
    for (int i = 0; i < 4; ++i)
        #pragma unroll
        for (int r = 0; r < 4; ++r) { s2[i][r] = 0.f; q2[i][r] = 0.f; }

    #pragma unroll 1
    for (int it = 0; it < 4; ++it) {
        int tile = it * 2048 + blockIdx.x * 2 + wslot;
        int base = tile * 64;
        bf16x8 B1[4];
        #pragma unroll
        for (int nt = 0; nt < 4; ++nt) {
            uint4 v = make_uint4(0u, 0u, 0u, 0u);
            if (qd == 0) v = fbf[base + nt * 16 + p];
            B1[nt] = asfrag(v);
        }
        #pragma unroll
        for (int mt = 0; mt < 4; ++mt) {
            bf16x8 A = asfrag(w1f[mt * 64 + lane]);
            float4 av = *(const float4*)(a1ls + mt * 16 + qd * 4);
            float4 cv = *(const float4*)(c1ls + mt * 16 + qd * 4);
            #pragma unroll
            for (int nt = 0; nt < 4; ++nt) {
                f32x4 acc = {0.f, 0.f, 0.f, 0.f};
                acc = __builtin_amdgcn_mfma_f32_16x16x32_bf16(A, B1[nt], acc, 0, 0, 0);
                float y0 = fmaxf(fmaf(av.x, acc[0], cv.x), 0.f);
                float y1 = fmaxf(fmaf(av.y, acc[1], cv.y), 0.f);
                float y2 = fmaxf(fmaf(av.z, acc[2], cv.z), 0.f);
                float y3 = fmaxf(fmaf(av.w, acc[3], cv.w), 0.f);
                int a = (nt * 16 + p) * YSTR + mt * 8 + qd * 2;
                *(uint2*)&my[a] = make_uint2(pkbf(y0, y1), pkbf(y2, y3));
            }
        }
        __syncthreads();   // y1 writes -> B2 reads
        bf16x8 B2[4][2];
        #pragma unroll
        for (int nt = 0; nt < 4; ++nt)
            #pragma unroll
            for (int kf = 0; kf < 2; ++kf)
                B2[nt][kf] = asfrag(*(const uint4*)&my[(nt * 16 + p) * YSTR + kf * 16 + qd * 4]);
        __syncthreads();   // B2 reads -> x2 LDS overwrite
        #pragma unroll
        for (int mt = 0; mt < 4; ++mt) {
            f32x4 acc[4];
            #pragma unroll
            for (int nt = 0; nt < 4; ++nt) acc[nt] = (f32x4){0.f, 0.f, 0.f, 0.f};
            #pragma unroll
            for (int kf = 0; kf < 2; ++kf) {
                bf16x8 W = asfrag(w2f[(mt * 2 + kf) * 64 + lane]);
                #pragma unroll
                for (int nt = 0; nt < 4; ++nt)
                    acc[nt] = __builtin_amdgcn_mfma_f32_16x16x32_bf16(W, B2[nt][kf], acc[nt], 0, 0, 0);
            }
            if (store_x2) {
                #pragma unroll
                for (int nt = 0; nt < 4; ++nt) {
                    int a = (nt * 16 + p) * YSTR + mt * 8 + qd * 2;
                    *(uint2*)&my[a] = make_uint2(pkbf(acc[nt][0], acc[nt][1]),
                                                 pkbf(acc[nt][2], acc[nt][3]));
                }
            }
            #pragma unroll
            for (int r = 0; r < 4; ++r) {
                float u0 = acc[0][r], u1 = acc[1][r], u2 = acc[2][r], u3 = acc[3][r];
                s2[mt][r] += (u0 + u1) + (u2 + u3);
                q2[mt][r] = fmaf(u0, u0, fmaf(u1, u1, fmaf(u2, u2, fmaf(u3, u3, q2[mt][r]))));
            }
        }
        if (store_x2) {
            __syncthreads();   // x2 LDS writes -> frag reads
            #pragma unroll
            for (int mtc = 0; mtc < 4; ++mtc)
                #pragma unroll
                for (int kf = 0; kf < 2; ++kf) {
                    uint4 v = *(const uint4*)&my[(mtc * 16 + p) * YSTR + kf * 16 + qd * 4];
                    x2a[((size_t)tile * 8 + mtc * 2 + kf) * 64 + lane] = v;   // 1 KB coalesced
                }
        }
        __syncthreads();   // tile done -> next iter overwrites LDS
    }
    #pragma unroll
    for (int mt = 0; mt < 4; ++mt)
        #pragma unroll
        for (int r = 0; r < 4; ++r) {
            float s = s2[mt][r], q = q2[mt][r];
            #pragma unroll
            for (int off = 1; off <= 8; off <<= 1) { s += __shfl_xor(s, off); q += __shfl_xor(q, off); }
            if (p == 0) {
                atomicAdd(&bs[mt * 16 + qd * 4 + r], s);
                atomicAdd(&bq[mt * 16 + qd * 4 + r], q);
            }
        }
    __syncthreads();
    if (tid < C2) { atomicAdd(&st[64 + tid], bs[tid]); atomicAdd(&st[128 + tid], bq[tid]); }
}

// ---------------- P3 (split): layer-3 only; 4 tiles/wave, tile double-buffer ----------------
__global__ __launch_bounds__(256) void k_p3_l3(
        const uint4* __restrict__ x2a, const uint4* __restrict__ wpk,
        float* __restrict__ st,
        const float* __restrict__ g2, const float* __restrict__ b2,
        const float* __restrict__ g3, float* __restrict__ gmm) {
    __shared__ uint4 w3ls[1024];
    __shared__ float bs[C3], bq[C3];
    __shared__ float a2ls[C2], c2ls[C2];
    int tid = threadIdx.x, wslot = tid >> 6, lane = tid & 63;
    int p = lane & 15, qd = lane >> 4;
    if (tid < 128) bs[tid] = 0.f; else bq[tid - 128] = 0.f;
    #pragma unroll
    for (int i = 0; i < 4; ++i) w3ls[i * 256 + tid] = wpk[768 + i * 256 + tid];
    if (tid < C2) fin_ch(st + 64, st + 128, g2, b2, tid, a2ls, c2ls);
    __syncthreads();
    float a2r[2][8], c2r[2][8];
    #pragma unroll
    for (int kf = 0; kf < 2; ++kf)
        #pragma unroll
        for (int j = 0; j < 8; ++j) {
            a2r[kf][j] = a2ls[kf * 32 + qd * 8 + j];
            c2r[kf][j] = c2ls[kf * 32 + qd * 8 + j];
        }
    float gs3[8], gq3[8];
    bool pos[8];
    #pragma unroll
    for (int i = 0; i < 8; ++i) { gs3[i] = 0.f; gq3[i] = 0.f; pos[i] = g3[i * 16 + p] >= 0.f; }

    int wv = blockIdx.x * 4 + wslot;        // grid 512 -> 2048 waves, 4 tiles each
    size_t cb = (size_t)wv * 4 * 8;         // chunk base of first tile

    uint4 cur[8], nxt[8];
    #pragma unroll
    for (int i = 0; i < 8; ++i) cur[i] = x2a[(cb + i) * 64 + lane];

    #pragma unroll 1
    for (int t = 0; t < 4; ++t) {
        int tile = wv * 4 + t;
        if (t < 3) {                        // deep prefetch: whole next tile (8 KB/wave in flight)
            #pragma unroll
            for (int i = 0; i < 8; ++i) nxt[i] = x2a[(cb + (t + 1) * 8 + i) * 64 + lane];
        }
        // repack all 4 mt up-front: affine+relu on bf16 pairs -> A-frags
        bf16x8 A[4][2];
        #pragma unroll
        for (int mt = 0; mt < 4; ++mt)
            #pragma unroll
            for (int kf = 0; kf < 2; ++kf) {
                uint4 u = cur[mt * 2 + kf];
                unsigned w[4] = { u.x, u.y, u.z, u.w };
                unsigned r[4];
                #pragma unroll
                for (int wi = 0; wi < 4; ++wi) {
                    float lo = bflo(w[wi]), hi = bfhi(w[wi]);
                    r[wi] = pkbf(fmaxf(fmaf(a2r[kf][2 * wi], lo, c2r[kf][2 * wi]), 0.f),
                                 fmaxf(fmaf(a2r[kf][2 * wi + 1], hi, c2r[kf][2 * wi + 1]), 0.f));
                }
                uint4 o = make_uint4(r[0], r[1], r[2], r[3]);
                A[mt][kf] = asfrag(o);
            }
        // nt-outer: W3 frags read once per (tile, nt) -> 16 ds_read_b128/tile
        float va[2][8];
        #pragma unroll
        for (int nt = 0; nt < 8; ++nt) {
            bf16x8 Wa = asfrag(w3ls[(nt * 2 + 0) * 64 + lane]);
            bf16x8 Wb = asfrag(w3ls[(nt * 2 + 1) * 64 + lane]);
            #pragma unroll
            for (int mt = 0; mt < 4; ++mt) {
                f32x4 acc = __builtin_amdgcn_mfma_f32_16x16x32_bf16(A[mt][0], Wa,
                                (f32x4){0.f, 0.f, 0.f, 0.f}, 0, 0, 0);
                acc = __builtin_amdgcn_mfma_f32_16x16x32_bf16(A[mt][1], Wb, acc, 0, 0, 0);
                float v0 = acc[0], v1 = acc[1], v2 = acc[2], v3 = acc[3];
                gs3[nt] += (v0 + v1) + (v2 + v3);
                gq3[nt] = fmaf(v0, v0, fmaf(v1, v1, fmaf(v2, v2, fmaf(v3, v3, gq3[nt]))));
                float mx = fmaxf(fmaxf(v0, v1), fmaxf(v2, v3));
                float mn = fminf(fminf(v0, v1), fminf(v2, v3));
                float vv = pos[nt] ? mx : -mn;   // negate-min: always fmax-reduce
                int g = mt >> 1;
                if ((mt & 1) == 0) va[g][nt] = vv;
                else va[g][nt] = fmaxf(va[g][nt], vv);
            }
        }
        // per-tile extremum reduce over qd + store
        #pragma unroll
        for (int nt = 0; nt < 8; ++nt) {
            float x = va[0][nt], y = va[1][nt];
            x = fmaxf(x, __shfl_xor(x, 16)); x = fmaxf(x, __shfl_xor(x, 32));
            y = fmaxf(y, __shfl_xor(y, 16)); y = fmaxf(y, __shfl_xor(y, 32));
            if (lane < 16) {
                gmm[(size_t)(tile * 2 + 0) * C3 + nt * 16 + lane] = x;
                gmm[(size_t)(tile * 2 + 1) * C3 + nt * 16 + lane] = y;
            }
        }
        if (t < 3) {
            #pragma unroll
            for (int i = 0; i < 8; ++i) cur[i] = nxt[i];
        }
    }
    // stats reduce over qd + block + global
    #pragma unroll
    for (int nt = 0; nt < 8; ++nt) {
        float s = gs3[nt], q = gq3[nt];
        s += __shfl_xor(s, 16); s += __shfl_xor(s, 32);
        q += __shfl_xor(q, 16); q += __shfl_xor(q, 32);
        if (lane < 16) {
            atomicAdd(&bs[nt * 16 + lane], s);
            atomicAdd(&bq[nt * 16 + lane], q);
        }
    }
    __syncthreads();
    if (tid < C3) { atomicAdd(&st[192 + tid], bs[tid]); atomicAdd(&st[320 + tid], bq[tid]); }
}

// ---------------- P3 (fallback, ws too small): fused 3 layers, R4-style barriers ----------------
__global__ __launch_bounds__(256) void k_p3_fused(
        const uint4* __restrict__ fbf, const uint4* __restrict__ wpk,
        float* __restrict__ st,
        const float* __restrict__ W1, const float* __restrict__ g1, const float* __restrict__ b1,
        const float* __restrict__ g2, const float* __restrict__ b2,
        const float* __restrict__ g3, float* __restrict__ gmm) {
    __shared__ unsigned yls[4][64 * YSTR];
    __shared__ uint4 w3ls[1024];
    __shared__ float bs[C3], bq[C3];
    __shared__ float a1ls[C1], c1ls[C1], a2ls[C2], c2ls[C2];
    int tid = threadIdx.x, wslot = tid >> 6, lane = tid & 63;
    int p = lane & 15, qd = lane >> 4;
    if (tid < 128) bs[tid] = 0.f; else bq[tid - 128] = 0.f;
    #pragma unroll
    for (int i = 0; i < 4; ++i) w3ls[i * 256 + tid] = wpk[768 + i * 256 + tid];
    if (tid < 64) fin1_ch(st, W1, g1, b1, tid, a1ls, c1ls);
    else if (tid < 128) fin_ch(st + 64, st + 128, g2, b2, tid - 64, a2ls, c2ls);
    __syncthreads();
    const uint4* w1f = wpk;
    const uint4* w2f = wpk + 256;
    unsigned* my = yls[wslot];
    float gs3[8], gq3[8];
    bool pos[8];
    #pragma unroll
    for (int i = 0; i < 8; ++i) { gs3[i] = 0.f; gq3[i] = 0.f; pos[i] = g3[i * 16 + p] >= 0.f; }

    #pragma unroll 1
    for (int it = 0; it < 2; ++it) {
        int tile = it * 4096 + blockIdx.x * 4 + wslot;
        int base = tile * 64;
        bf16x8 B1[4];
        #pragma unroll
        for (int nt = 0; nt < 4; ++nt) {
            uint4 v = make_uint4(0u, 0u, 0u, 0u);
            if (qd == 0) v = fbf[base + nt * 16 + p];
            B1[nt] = asfrag(v);
        }
        #pragma unroll
        for (int mt = 0; mt < 4; ++mt) {
            bf16x8 Aw = asfrag(w1f[mt * 64 + lane]);
            float4 av = *(const float4*)(a1ls + mt * 16 + qd * 4);
            float4 cv = *(const float4*)(c1ls + mt * 16 + qd * 4);
            #pragma unroll
            for (int nt = 0; nt < 4; ++nt) {
                f32x4 acc = {0.f, 0.f, 0.f, 0.f};
                acc = __builtin_amdgcn_mfma_f32_16x16x32_bf16(Aw, B1[nt], acc, 0, 0, 0);
                float y0 = fmaxf(fmaf(av.x, acc[0], cv.x), 0.f);
                float y1 = fmaxf(fmaf(av.y, acc[1], cv.y), 0.f);
                float y2 = fmaxf(fmaf(av.z, acc[2], cv.z), 0.f);
                float y3 = fmaxf(fmaf(av.w, acc[3], cv.w), 0.f);
                int a = (nt * 16 + p) * YSTR + mt * 8 + qd * 2;
                *(uint2*)&my[a] = make_uint2(pkbf(y0, y1), pkbf(y2, y3));
            }
        }
        __syncthreads();
        bf16x8 B2[4][2];
        #pragma unroll
        for (int nt = 0; nt < 4; ++nt)
            #pragma unroll
            for (int kf = 0; kf < 2; ++kf)
                B2[nt][kf] = asfrag(*(const uint4*)&my[(nt * 16 + p) * YSTR + kf * 16 + qd * 4]);
        __syncthreads();
        #pragma unroll
        for (int mt = 0; mt < 4; ++mt) {
            f32x4 acc[4];
            #pragma unroll
            for (int nt = 0; nt < 4; ++nt) acc[nt] = (f32x4){0.f, 0.f, 0.f, 0.f};
            #pragma unroll
            for (int kf = 0; kf < 2; ++kf) {
                bf16x8 W = asfrag(w2f[(mt * 2 + kf) * 64 + lane]);
                #pragma unroll
                for (int nt = 0; nt < 4; ++nt)
                    acc[nt] = __builtin_amdgcn_mfma_f32_16x16x32_bf16(W, B2[nt][kf], acc[nt], 0, 0, 0);
            }
            float4 av = *(const float4*)(a2ls + mt * 16 + qd * 4);
            float4 cv = *(const float4*)(c2ls + mt * 16 + qd * 4);
            #pragma unroll
            for (int nt = 0; nt < 4; ++nt) {
                float y0 = fmaxf(fmaf(av.x, acc[nt][0], cv.x), 0.f);
                float y1 = fmaxf(fmaf(av.y, acc[nt][1], cv.y), 0.f);
                float y2 = fmaxf(fmaf(av.z, acc[nt][2], cv.z), 0.f);
                float y3 = fmaxf(fmaf(av.w, acc[nt][3], cv.w), 0.f);
                int a = (nt * 16 + p) * YSTR + mt * 8 + qd * 2;
                *(uint2*)&my[a] = make_uint2(pkbf(y0, y1), pkbf(y2, y3));
            }
        }
        __syncthreads();
        bf16x8 A3[4][2];
        #pragma unroll
        for (int mt = 0; mt < 4; ++mt) {
            A3[mt][0] = asfrag(*(const uint4*)&my[(mt * 16 + p) * YSTR + qd * 4]);
            A3[mt][1] = asfrag(*(const uint4*)&my[(mt * 16 + p) * YSTR + 16 + qd * 4]);
        }
        __syncthreads();
        #pragma unroll
        for (int nt = 0; nt < 8; ++nt) {
            bf16x8 Wa = asfrag(w3ls[(nt * 2 + 0) * 64 + lane]);
            bf16x8 Wb = asfrag(w3ls[(nt * 2 + 1) * 64 + lane]);
            f32x4 acc[4];
            #pragma unroll
            for (int mt = 0; mt < 4; ++mt) {
                acc[mt] = __builtin_amdgcn_mfma_f32_16x16x32_bf16(A3[mt][0], Wa,
                            (f32x4){0.f, 0.f, 0.f, 0.f}, 0, 0, 0);
                acc[mt] = __builtin_amdgcn_mfma_f32_16x16x32_bf16(A3[mt][1], Wb, acc[mt], 0, 0, 0);
            }
            float s = 0.f, q = 0.f, va = 0.f, vb = 0.f;
            #pragma unroll
            for (int mt = 0; mt < 4; ++mt) {
                float v0 = acc[mt][0], v1 = acc[mt][1], v2 = acc[mt][2], v3 = acc[mt][3];
                s += (v0 + v1) + (v2 + v3);
                q = fmaf(v0, v0, fmaf(v1, v1, fmaf(v2, v2, fmaf(v3, v3, q))));
                float mx = fmaxf(fmaxf(v0, v1), fmaxf(v2, v3));
                float mn = fminf(fminf(v0, v1), fminf(v2, v3));
                float vv = pos[nt] ? mx : -mn;
                if (mt == 0) va = vv;
                else if (mt == 1) va = fmaxf(va, vv);
                else if (mt == 2) vb = vv;
                else vb = fmaxf(vb, vv);
            }
            gs3[nt] += s; gq3[nt] += q;
            va = fmaxf(va, __shfl_xor(va, 16)); va = fmaxf(va, __shfl_xor(va, 32));
            vb = fmaxf(vb, __shfl_xor(vb, 16)); vb = fmaxf(vb, __shfl_xor(vb, 32));
            if (lane < 16) {
                gmm[(size_t)(tile * 2 + 0) * C3 + nt * 16 + lane] = va;
                gmm[(size_t)(tile * 2 + 1) * C3 + nt * 16 + lane] = vb;
            }
        }
    }
    #pragma unroll
    for (int nt = 0; nt < 8; ++nt) {
        float s = gs3[nt], q = gq3[nt];
        s += __shfl_xor(s, 16); s += __shfl_xor(s, 32);
        q += __shfl_xor(q, 16); q += __shfl_xor(q, 32);
        if (lane < 16) {
            atomicAdd(&bs[nt * 16 + lane], s);
            atomicAdd(&bq[nt * 16 + lane], q);
        }
    }
    __syncthreads();
    if (tid < C3) { atomicAdd(&st[192 + tid], bs[tid]); atomicAdd(&st[320 + tid], bq[tid]); }
}

// ---------------- epilogue: fin3 inlined; coalesced gmm read; out + xyz ----------------
__global__ void k_outx(const float* __restrict__ gmm, const float* __restrict__ st,
                       const float* __restrict__ g3, const float* __restrict__ b3,
                       const float* __restrict__ xyz, const int* __restrict__ fps,
                       float* __restrict__ out) {
    __shared__ float T[C3][17];
    __shared__ float a3ls[C3], c3ls[C3];
    int blk = blockIdx.x, tid = threadIdx.x;
    if (blk < 1024) {
        if (tid < C3) fin_ch(st + 192, st + 320, g3, b3, tid, a3ls, c3ls);
        __syncthreads();
        int b = blk >> 7, s0 = (blk & 127) << 4;
        #pragma unroll
        for (int i = 0; i < 8; ++i) {
            int idx = i * 256 + tid;
            int sl = idx >> 7, o = idx & 127;
            float m = gmm[((size_t)(b * SS_ + s0 + sl)) * C3 + o];
            float a = a3ls[o];
            float v = (a >= 0.f) ? m : -m;
            T[o][sl] = fmaxf(fmaf(a, v, c3ls[o]), 0.f);
        }
        __syncthreads();
        int o = tid & 127, sh = tid >> 7;
        float* dst = out + (size_t)BB_ * 3 * SS_ + ((size_t)b * C3 + o) * SS_ + s0 + sh * 8;
        float4 w0, w1;
        w0.x = T[o][sh * 8 + 0]; w0.y = T[o][sh * 8 + 1];
        w0.z = T[o][sh * 8 + 2]; w0.w = T[o][sh * 8 + 3];
        w1.x = T[o][sh * 8 + 4]; w1.y = T[o][sh * 8 + 5];
        w1.z = T[o][sh * 8 + 6]; w1.w = T[o][sh * 8 + 7];
        *(float4*)dst = w0; *(float4*)(dst + 4) = w1;
    } else {
        int t = (blk - 1024) * 256 + tid;   // < 49152
        int b = t / (3 * SS_);
        int r = (t / SS_) % 3;
        int s = t % SS_;
        int ci = fps[b * SS_ + s];
        out[t] = xyz[((size_t)b * 3 + r) * NN_ + ci];
    }
}

extern "C" void kernel_launch(void* const* d_in, const int* in_sizes, int n_in,
                              void* d_out, int out_size, void* d_ws, size_t ws_size,
                              hipStream_t stream) {
    (void)in_sizes; (void)n_in; (void)out_size;
    const float* xyz = (const float*)d_in[0];
    const float* pts = (const float*)d_in[1];
    const int*   fps = (const int*)d_in[2];
    const float* W1 = (const float*)d_in[3];
    const float* g1 = (const float*)d_in[4];
    const float* b1 = (const float*)d_in[5];
    const float* W2 = (const float*)d_in[6];
    const float* g2 = (const float*)d_in[7];
    const float* b2 = (const float*)d_in[8];
    const float* W3 = (const float*)d_in[9];
    const float* g3 = (const float*)d_in[10];
    const float* b3 = (const float*)d_in[11];
    float* out = (float*)d_out;
    float* ws = (float*)d_ws;

    uint4* fbf = (uint4*)(ws + FBF_OFF);
    uint4* wpk = (uint4*)(ws + WPK_OFF);
    float* st  = ws + ST_OFF;
    float* gmm = ws + GMM_OFF;
    uint4* x2a = (uint4*)(ws + X2_OFF);
    int split = (ws_size >= WS_NEED) ? 1 : 0;   // constant across calls -> graph-safe

    k_front<<<4096 + 8, 256, 0, stream>>>(xyz, pts, fps, fbf, W1, W2, W3, wpk, st);
    k_p1<<<256, 256, 0, stream>>>(fbf, st);
    k_p2<<<1024, 128, 0, stream>>>(fbf, wpk, st, W1, g1, b1, x2a, split);
    if (split)
        k_p3_l3<<<512, 256, 0, stream>>>(x2a, wpk, st, g2, b2, g3, gmm);
    else
        k_p3_fused<<<1024, 256, 0, stream>>>(fbf, wpk, st, W1, g1, b1, g2, b2, g3, gmm);
    k_outx<<<1024 + 192, 256, 0, stream>>>(gmm, st, g3, b3, xyz, fps, out);
}